// Round 1
// baseline (481.033 us; speedup 1.0000x reference)
//
#include <hip/hip_runtime.h>
#include <hip/hip_bf16.h>

#define DIMX 1024
#define HID  2048
#define NE   8
#define NT   4096
#define NPAIR 8192

typedef __attribute__((ext_vector_type(8))) __bf16 bf16x8;
typedef __attribute__((ext_vector_type(4))) float f32x4;

__device__ inline unsigned short f2bf(float f) {
  union { float f; unsigned u; } v; v.f = f;
  unsigned r = v.u + 0x7FFFu + ((v.u >> 16) & 1u);
  return (unsigned short)(r >> 16);
}
__device__ inline float bf2f(unsigned short h) {
  union { unsigned u; float f; } v; v.u = ((unsigned)h) << 16;
  return v.f;
}

// ---------------- workspace layout (bytes) ----------------
#define O_CNT   0u            // 8 int
#define O_OFFS  256u          // 9 int
#define O_TOK   1024u         // 8*4096 int   = 131072
#define O_TK    (O_TOK + 131072u)
#define O_PW    (O_TK + 131072u)
#define O_XBF   524288u                       // 4096*1024 bf16 = 8 MB
#define O_W1T   16777216u                     // 8*2048*1024 bf16 = 33.5 MB
#define O_W2T   50331648u                     // 8*1024*2048 bf16 = 33.5 MB
#define O_H     83886080u                     // 8192*2048 bf16 = 33.5 MB
#define O_Y     117440512u                    // 8192*1024 f32  = 33.5 MB
// total ~151 MB

__global__ void k_zero(int* cnt) {
  if (threadIdx.x < NE) cnt[threadIdx.x] = 0;
}

// one wave per token: logits, top-2, renorm weights, scatter to expert lists
__global__ __launch_bounds__(64) void k_gate(const float* __restrict__ x,
                                             const float* __restrict__ gw,
                                             int* cnt, int* ptok, int* ptk, float* pw) {
  int t = blockIdx.x;
  int lane = threadIdx.x;
  float p[NE];
#pragma unroll
  for (int e = 0; e < NE; e++) p[e] = 0.f;
  const float* xr = x + (size_t)t * DIMX;
  for (int j = 0; j < DIMX / 64; j++) {
    int d = lane + j * 64;
    float xv = xr[d];
    const float4* g4 = (const float4*)(gw + (size_t)d * NE);
    float4 a = g4[0], b = g4[1];
    p[0] += xv * a.x; p[1] += xv * a.y; p[2] += xv * a.z; p[3] += xv * a.w;
    p[4] += xv * b.x; p[5] += xv * b.y; p[6] += xv * b.z; p[7] += xv * b.w;
  }
#pragma unroll
  for (int e = 0; e < NE; e++)
#pragma unroll
    for (int off = 32; off > 0; off >>= 1) p[e] += __shfl_xor(p[e], off);
  if (lane == 0) {
    int ia = 0; float va = p[0];
#pragma unroll
    for (int e = 1; e < NE; e++) if (p[e] > va) { va = p[e]; ia = e; }
    int ib = -1; float vb = -3.0e38f;
#pragma unroll
    for (int e = 0; e < NE; e++) { if (e == ia) continue; if (p[e] > vb) { vb = p[e]; ib = e; } }
    // softmax-renormalized top-2 == 2-way softmax over top-2 logits
    float w0 = 1.f / (1.f + expf(vb - va));
    float w1 = 1.f - w0;
    int pos = atomicAdd(&cnt[ia], 1);
    ptok[ia * NT + pos] = t; ptk[ia * NT + pos] = t * 2;     pw[ia * NT + pos] = w0;
    pos = atomicAdd(&cnt[ib], 1);
    ptok[ib * NT + pos] = t; ptk[ib * NT + pos] = t * 2 + 1; pw[ib * NT + pos] = w1;
  }
}

__global__ void k_offs(const int* cnt, int* offs) {
  if (threadIdx.x == 0) {
    int s = 0;
    for (int e = 0; e < NE; e++) { offs[e] = s; s += cnt[e]; }
    offs[NE] = s;
  }
}

// out[c][r] = bf16(in[r][c]) per expert slice (R,C multiples of 32)
__global__ __launch_bounds__(256) void k_transpose_cvt(const float* __restrict__ in,
                                                       unsigned short* __restrict__ out,
                                                       int R, int C) {
  __shared__ float tile[32][33];
  int e = blockIdx.z;
  const float* ip = in + (size_t)e * R * C;
  unsigned short* op = out + (size_t)e * R * C;
  int tx = threadIdx.x & 31, ty = threadIdx.x >> 5;
  int c = blockIdx.x * 32 + tx;
  int r0 = blockIdx.y * 32;
#pragma unroll
  for (int i = 0; i < 4; i++) tile[ty + i * 8][tx] = ip[(size_t)(r0 + ty + i * 8) * C + c];
  __syncthreads();
  int r = r0 + tx;
#pragma unroll
  for (int i = 0; i < 4; i++)
    op[(size_t)(blockIdx.x * 32 + ty + i * 8) * R + r] = f2bf(tile[tx][ty + i * 8]);
}

__global__ __launch_bounds__(256) void k_cvt(const float* __restrict__ in,
                                             unsigned short* __restrict__ out, int n4) {
  int i = blockIdx.x * blockDim.x + threadIdx.x;
  if (i < n4) {
    float4 v = ((const float4*)in)[i];
    ushort4 o; o.x = f2bf(v.x); o.y = f2bf(v.y); o.z = f2bf(v.z); o.w = f2bf(v.w);
    ((ushort4*)out)[i] = o;
  }
}

#define BM 128
#define BN 128
#define BK 32
#define LDSP 40   // padded k-stride (bf16 elems): 80B rows -> conflict-free b128 frags

// GEMM1: hpre[offs[e]+pos][:] = gathered_x[tok] @ w1T[e]^T + b1[e]
__global__ __launch_bounds__(256) void k_gemm1(
    const unsigned short* __restrict__ xbf,   // [NT][DIMX] bf16
    const unsigned short* __restrict__ w1t,   // [E][HID][DIMX] bf16 (n-major, k-contig)
    const float* __restrict__ bias1,          // [E][HID]
    const int* __restrict__ cnt, const int* __restrict__ offs,
    const int* __restrict__ ptok,
    unsigned short* __restrict__ hpre)        // [NPAIR][HID] bf16
{
  int e = blockIdx.z;
  int n_e = cnt[e];
  int row0 = blockIdx.y * BM;
  if (row0 >= n_e) return;
  int col0 = blockIdx.x * BN;
  int offs_e = offs[e];

  __shared__ __align__(16) unsigned short As[BM][LDSP];
  __shared__ __align__(16) unsigned short Bs[BN][LDSP];

  int tid = threadIdx.x;
  int lane = tid & 63, wid = tid >> 6;
  int wr = wid >> 1, wc = wid & 1;
  int quad = lane >> 4, m16 = lane & 15;

  // staging: chunks tid and tid+256; chunk -> (row = c>>2, kc = c&3)
  int r0 = tid >> 2, kc = tid & 3;
  int r1 = r0 + 64;
  int g0 = row0 + r0, g1 = row0 + r1;
  int t0 = (g0 < n_e) ? ptok[e * NT + g0] : 0;
  int t1 = (g1 < n_e) ? ptok[e * NT + g1] : 0;
  const unsigned short* a0p = xbf + (size_t)t0 * DIMX + kc * 8;
  const unsigned short* a1p = xbf + (size_t)t1 * DIMX + kc * 8;
  const unsigned short* bb = w1t + (size_t)e * HID * DIMX;
  const unsigned short* b0p = bb + (size_t)(col0 + r0) * DIMX + kc * 8;
  const unsigned short* b1p = bb + (size_t)(col0 + r1) * DIMX + kc * 8;

  f32x4 acc[4][4];
#pragma unroll
  for (int i = 0; i < 4; i++)
#pragma unroll
    for (int j = 0; j < 4; j++) acc[i][j] = (f32x4)(0.f);

  for (int k0 = 0; k0 < DIMX; k0 += BK) {
    __syncthreads();
    *(int4*)&As[r0][kc * 8] = *(const int4*)(a0p + k0);
    *(int4*)&As[r1][kc * 8] = *(const int4*)(a1p + k0);
    *(int4*)&Bs[r0][kc * 8] = *(const int4*)(b0p + k0);
    *(int4*)&Bs[r1][kc * 8] = *(const int4*)(b1p + k0);
    __syncthreads();
    bf16x8 af[4], bfr[4];
#pragma unroll
    for (int i = 0; i < 4; i++) af[i]  = *(const bf16x8*)&As[wr * 64 + i * 16 + m16][quad * 8];
#pragma unroll
    for (int i = 0; i < 4; i++) bfr[i] = *(const bf16x8*)&Bs[wc * 64 + i * 16 + m16][quad * 8];
#pragma unroll
    for (int i = 0; i < 4; i++)
#pragma unroll
      for (int j = 0; j < 4; j++)
        acc[i][j] = __builtin_amdgcn_mfma_f32_16x16x32_bf16(af[i], bfr[j], acc[i][j], 0, 0, 0);
  }

#pragma unroll
  for (int i = 0; i < 4; i++) {
#pragma unroll
    for (int r = 0; r < 4; r++) {
      int rl = wr * 64 + i * 16 + quad * 4 + r;
      int g = row0 + rl;
      if (g < n_e) {
        size_t rowbase = (size_t)(offs_e + g) * HID;
#pragma unroll
        for (int j = 0; j < 4; j++) {
          int colg = col0 + wc * 64 + j * 16 + m16;
          float val = acc[i][j][r] + bias1[e * HID + colg];
          hpre[rowbase + colg] = f2bf(val);
        }
      }
    }
  }
}

// in-place row LayerNorm + exact GELU over HID
__global__ __launch_bounds__(256) void k_ln_gelu(unsigned short* __restrict__ h,
                                                 const float* __restrict__ g1,
                                                 const float* __restrict__ bb1,
                                                 const int* __restrict__ offs) {
  __shared__ float sbuf[4];
  int row = blockIdx.x;
  int tid = threadIdx.x;
  int e = 0;
#pragma unroll
  for (int i = 1; i < NE; i++) if (row >= offs[i]) e = i;
  unsigned short* p = h + (size_t)row * HID;
  float v[8];
#pragma unroll
  for (int i = 0; i < 8; i++) v[i] = bf2f(p[tid + i * 256]);
  float s = 0.f;
#pragma unroll
  for (int i = 0; i < 8; i++) s += v[i];
#pragma unroll
  for (int off = 32; off > 0; off >>= 1) s += __shfl_xor(s, off);
  if ((tid & 63) == 0) sbuf[tid >> 6] = s;
  __syncthreads();
  float mean = (sbuf[0] + sbuf[1] + sbuf[2] + sbuf[3]) * (1.f / HID);
  float sq = 0.f;
#pragma unroll
  for (int i = 0; i < 8; i++) { float d = v[i] - mean; sq += d * d; }
#pragma unroll
  for (int off = 32; off > 0; off >>= 1) sq += __shfl_xor(sq, off);
  __syncthreads();
  if ((tid & 63) == 0) sbuf[tid >> 6] = sq;
  __syncthreads();
  float var = (sbuf[0] + sbuf[1] + sbuf[2] + sbuf[3]) * (1.f / HID);
  float rstd = rsqrtf(var + 1e-5f);
#pragma unroll
  for (int i = 0; i < 8; i++) {
    int d = tid + i * 256;
    float xn = (v[i] - mean) * rstd * g1[(size_t)e * HID + d] + bb1[(size_t)e * HID + d];
    float ge = 0.5f * xn * (1.f + erff(xn * 0.7071067811865476f));
    p[d] = f2bf(ge);
  }
}

// GEMM2: ybuf[tk] = (h_row @ w2T[e]^T + b2[e]) * gate_weight
__global__ __launch_bounds__(256) void k_gemm2(
    const unsigned short* __restrict__ hb,    // [NPAIR][HID] bf16
    const unsigned short* __restrict__ w2t,   // [E][DIMX][HID] bf16
    const float* __restrict__ bias2,          // [E][DIMX]
    const int* __restrict__ cnt, const int* __restrict__ offs,
    const int* __restrict__ ptk, const float* __restrict__ pw,
    float* __restrict__ ybuf)                 // [NPAIR][DIMX] f32
{
  int e = blockIdx.z;
  int n_e = cnt[e];
  int row0 = blockIdx.y * BM;
  if (row0 >= n_e) return;
  int col0 = blockIdx.x * BN;
  int offs_e = offs[e];

  __shared__ __align__(16) unsigned short As[BM][LDSP];
  __shared__ __align__(16) unsigned short Bs[BN][LDSP];

  int tid = threadIdx.x;
  int lane = tid & 63, wid = tid >> 6;
  int wr = wid >> 1, wc = wid & 1;
  int quad = lane >> 4, m16 = lane & 15;

  int r0 = tid >> 2, kc = tid & 3;
  int r1 = r0 + 64;
  int g0 = row0 + r0; if (g0 >= n_e) g0 = 0;
  int g1 = row0 + r1; if (g1 >= n_e) g1 = 0;
  const unsigned short* a0p = hb + (size_t)(offs_e + g0) * HID + kc * 8;
  const unsigned short* a1p = hb + (size_t)(offs_e + g1) * HID + kc * 8;
  const unsigned short* bb = w2t + (size_t)e * DIMX * HID;
  const unsigned short* b0p = bb + (size_t)(col0 + r0) * HID + kc * 8;
  const unsigned short* b1p = bb + (size_t)(col0 + r1) * HID + kc * 8;

  f32x4 acc[4][4];
#pragma unroll
  for (int i = 0; i < 4; i++)
#pragma unroll
    for (int j = 0; j < 4; j++) acc[i][j] = (f32x4)(0.f);

  for (int k0 = 0; k0 < HID; k0 += BK) {
    __syncthreads();
    *(int4*)&As[r0][kc * 8] = *(const int4*)(a0p + k0);
    *(int4*)&As[r1][kc * 8] = *(const int4*)(a1p + k0);
    *(int4*)&Bs[r0][kc * 8] = *(const int4*)(b0p + k0);
    *(int4*)&Bs[r1][kc * 8] = *(const int4*)(b1p + k0);
    __syncthreads();
    bf16x8 af[4], bfr[4];
#pragma unroll
    for (int i = 0; i < 4; i++) af[i]  = *(const bf16x8*)&As[wr * 64 + i * 16 + m16][quad * 8];
#pragma unroll
    for (int i = 0; i < 4; i++) bfr[i] = *(const bf16x8*)&Bs[wc * 64 + i * 16 + m16][quad * 8];
#pragma unroll
    for (int i = 0; i < 4; i++)
#pragma unroll
      for (int j = 0; j < 4; j++)
        acc[i][j] = __builtin_amdgcn_mfma_f32_16x16x32_bf16(af[i], bfr[j], acc[i][j], 0, 0, 0);
  }

#pragma unroll
  for (int i = 0; i < 4; i++) {
#pragma unroll
    for (int r = 0; r < 4; r++) {
      int rl = wr * 64 + i * 16 + quad * 4 + r;
      int g = row0 + rl;
      if (g < n_e) {
        int pi = e * NT + g;
        float w = pw[pi];
        size_t obase = (size_t)ptk[pi] * DIMX;
#pragma unroll
        for (int j = 0; j < 4; j++) {
          int colg = col0 + wc * 64 + j * 16 + m16;
          ybuf[obase + colg] = (acc[i][j][r] + bias2[e * DIMX + colg]) * w;
        }
      }
    }
  }
}

// out = LN(y_slot0 + y_slot1 + x) with ln_g/ln_b
__global__ __launch_bounds__(256) void k_final(const float* __restrict__ yb,
                                               const float* __restrict__ x,
                                               const float* __restrict__ lg,
                                               const float* __restrict__ lb,
                                               float* __restrict__ out) {
  __shared__ float sbuf[4];
  int t = blockIdx.x, tid = threadIdx.x;
  const float4* y0 = (const float4*)(yb + (size_t)t * 2 * DIMX);
  const float4* y1 = y0 + DIMX / 4;
  const float4* x4 = (const float4*)(x + (size_t)t * DIMX);
  float4 a = y0[tid], b = y1[tid], c = x4[tid];
  float4 v; v.x = a.x + b.x + c.x; v.y = a.y + b.y + c.y;
  v.z = a.z + b.z + c.z; v.w = a.w + b.w + c.w;
  float s = v.x + v.y + v.z + v.w;
#pragma unroll
  for (int off = 32; off > 0; off >>= 1) s += __shfl_xor(s, off);
  if ((tid & 63) == 0) sbuf[tid >> 6] = s;
  __syncthreads();
  float mean = (sbuf[0] + sbuf[1] + sbuf[2] + sbuf[3]) * (1.f / DIMX);
  float dx = v.x - mean, dy = v.y - mean, dz = v.z - mean, dw = v.w - mean;
  float sq = dx * dx + dy * dy + dz * dz + dw * dw;
#pragma unroll
  for (int off = 32; off > 0; off >>= 1) sq += __shfl_xor(sq, off);
  __syncthreads();
  if ((tid & 63) == 0) sbuf[tid >> 6] = sq;
  __syncthreads();
  float var = (sbuf[0] + sbuf[1] + sbuf[2] + sbuf[3]) * (1.f / DIMX);
  float rstd = rsqrtf(var + 1e-5f);
  float4 g = ((const float4*)lg)[tid], bb = ((const float4*)lb)[tid];
  float4 o; o.x = dx * rstd * g.x + bb.x; o.y = dy * rstd * g.y + bb.y;
  o.z = dz * rstd * g.z + bb.z; o.w = dw * rstd * g.w + bb.w;
  ((float4*)(out + (size_t)t * DIMX))[tid] = o;
}

extern "C" void kernel_launch(void* const* d_in, const int* in_sizes, int n_in,
                              void* d_out, int out_size, void* d_ws, size_t ws_size,
                              hipStream_t stream) {
  const float* x     = (const float*)d_in[0];
  const float* gw    = (const float*)d_in[1];
  const float* w1    = (const float*)d_in[2];
  const float* b1    = (const float*)d_in[3];
  const float* ln1g  = (const float*)d_in[4];
  const float* ln1b  = (const float*)d_in[5];
  const float* w2    = (const float*)d_in[6];
  const float* b2    = (const float*)d_in[7];
  const float* lng   = (const float*)d_in[8];
  const float* lnb   = (const float*)d_in[9];
  float* out = (float*)d_out;

  char* ws = (char*)d_ws;
  int* cnt  = (int*)(ws + O_CNT);
  int* offs = (int*)(ws + O_OFFS);
  int* ptok = (int*)(ws + O_TOK);
  int* ptk  = (int*)(ws + O_TK);
  float* pw = (float*)(ws + O_PW);
  unsigned short* xbf = (unsigned short*)(ws + O_XBF);
  unsigned short* w1t = (unsigned short*)(ws + O_W1T);
  unsigned short* w2t = (unsigned short*)(ws + O_W2T);
  unsigned short* hpre = (unsigned short*)(ws + O_H);
  float* ybuf = (float*)(ws + O_Y);

  hipLaunchKernelGGL(k_zero, dim3(1), dim3(64), 0, stream, cnt);
  hipLaunchKernelGGL(k_gate, dim3(NT), dim3(64), 0, stream, x, gw, cnt, ptok, ptk, pw);
  hipLaunchKernelGGL(k_offs, dim3(1), dim3(64), 0, stream, cnt, offs);
  // bf16 conversions / transposes
  hipLaunchKernelGGL(k_cvt, dim3(NT * DIMX / 4 / 256), dim3(256), 0, stream, x, xbf, NT * DIMX / 4);
  hipLaunchKernelGGL(k_transpose_cvt, dim3(HID / 32, DIMX / 32, NE), dim3(256), 0, stream,
                     w1, w1t, DIMX, HID);
  hipLaunchKernelGGL(k_transpose_cvt, dim3(DIMX / 32, HID / 32, NE), dim3(256), 0, stream,
                     w2, w2t, HID, DIMX);
  // expert FFN
  hipLaunchKernelGGL(k_gemm1, dim3(HID / BN, NT / BM, NE), dim3(256), 0, stream,
                     xbf, w1t, b1, cnt, offs, ptok, hpre);
  hipLaunchKernelGGL(k_ln_gelu, dim3(NPAIR), dim3(256), 0, stream, hpre, ln1g, ln1b, offs);
  hipLaunchKernelGGL(k_gemm2, dim3(DIMX / BN, NT / BM, NE), dim3(256), 0, stream,
                     hpre, w2t, b2, cnt, offs, ptk, pw, ybuf);
  hipLaunchKernelGGL(k_final, dim3(NT), dim3(256), 0, stream, ybuf, x, lng, lnb, out);
}

// Round 2
// 436.511 us; speedup vs baseline: 1.1020x; 1.1020x over previous
//
#include <hip/hip_runtime.h>
#include <hip/hip_bf16.h>

#define DIMX 1024
#define HID  2048
#define NE   8
#define NT   4096
#define NPAIR 8192

typedef __attribute__((ext_vector_type(8))) __bf16 bf16x8;
typedef __attribute__((ext_vector_type(4))) float f32x4;

__device__ inline unsigned short f2bf(float f) {
  union { float f; unsigned u; } v; v.f = f;
  unsigned r = v.u + 0x7FFFu + ((v.u >> 16) & 1u);
  return (unsigned short)(r >> 16);
}
__device__ inline float bf2f(unsigned short h) {
  union { unsigned u; float f; } v; v.u = ((unsigned)h) << 16;
  return v.f;
}

// ---------------- workspace layout (bytes) ----------------
#define O_CNT   0u            // 8 int
#define O_OFFS  256u          // 9 int
#define O_TOK   1024u         // 8*4096 int
#define O_TK    (O_TOK + 131072u)
#define O_PW    (O_TK + 131072u)
#define O_TI    (O_PW + 131072u)             // 8192 int  (per-pair expert id)
#define O_TW    (O_TI + 32768u)              // 8192 float (per-pair weight)
#define O_XBF   524288u                       // 4096*1024 bf16 = 8 MB
#define O_W1T   16777216u                     // 8*2048*1024 bf16 = 33.5 MB
#define O_W2T   50331648u                     // 8*1024*2048 bf16 = 33.5 MB
#define O_H     83886080u                     // 8192*2048 bf16 = 33.5 MB
#define O_Y     117440512u                    // 8192*1024 f32  = 33.5 MB

// one wave per token: logits, top-2, renorm weights -> per-pair (expert, weight)
__global__ __launch_bounds__(64) void k_gate_top2(const float* __restrict__ x,
                                                  const float* __restrict__ gw,
                                                  int* __restrict__ ti,
                                                  float* __restrict__ tw) {
  int t = blockIdx.x;
  int lane = threadIdx.x;
  float p[NE];
#pragma unroll
  for (int e = 0; e < NE; e++) p[e] = 0.f;
  const float* xr = x + (size_t)t * DIMX;
  for (int j = 0; j < DIMX / 64; j++) {
    int d = lane + j * 64;
    float xv = xr[d];
    const float4* g4 = (const float4*)(gw + (size_t)d * NE);
    float4 a = g4[0], b = g4[1];
    p[0] += xv * a.x; p[1] += xv * a.y; p[2] += xv * a.z; p[3] += xv * a.w;
    p[4] += xv * b.x; p[5] += xv * b.y; p[6] += xv * b.z; p[7] += xv * b.w;
  }
#pragma unroll
  for (int e = 0; e < NE; e++)
#pragma unroll
    for (int off = 32; off > 0; off >>= 1) p[e] += __shfl_xor(p[e], off);
  if (lane == 0) {
    int ia = 0; float va = p[0];
#pragma unroll
    for (int e = 1; e < NE; e++) if (p[e] > va) { va = p[e]; ia = e; }
    int ib = -1; float vb = -3.0e38f;
#pragma unroll
    for (int e = 0; e < NE; e++) { if (e == ia) continue; if (p[e] > vb) { vb = p[e]; ib = e; } }
    // softmax-renormalized top-2 == 2-way softmax over the top-2 logits
    float w0 = 1.f / (1.f + expf(vb - va));
    ti[t * 2] = ia;     tw[t * 2] = w0;
    ti[t * 2 + 1] = ib; tw[t * 2 + 1] = 1.f - w0;
  }
}

// single block, 8 waves (one per expert): deterministic stream compaction,
// zero global atomics. Pass 1: counts -> offsets. Pass 2: ballot-prefix scatter.
__global__ __launch_bounds__(512) void k_build(const int* __restrict__ ti,
                                               const float* __restrict__ tw,
                                               int* __restrict__ cnt, int* __restrict__ offs,
                                               int* __restrict__ ptok, int* __restrict__ ptk,
                                               float* __restrict__ pw) {
  __shared__ int scnt[NE];
  __shared__ int soffs[NE + 1];
  int wid = threadIdx.x >> 6;       // expert this wave handles
  int lane = threadIdx.x & 63;
  int c = 0;
  for (int p = lane; p < NPAIR; p += 64) c += (ti[p] == wid) ? 1 : 0;
#pragma unroll
  for (int off = 32; off > 0; off >>= 1) c += __shfl_xor(c, off);
  if (lane == 0) scnt[wid] = c;
  __syncthreads();
  if (threadIdx.x == 0) {
    int s = 0;
    for (int e = 0; e < NE; e++) { soffs[e] = s; s += scnt[e]; }
    soffs[NE] = s;
  }
  __syncthreads();
  if (threadIdx.x < NE) {
    cnt[threadIdx.x] = scnt[threadIdx.x];
    offs[threadIdx.x] = soffs[threadIdx.x];
  }
  if (threadIdx.x == 0) offs[NE] = soffs[NE];
  int base = 0;
  for (int p0 = 0; p0 < NPAIR; p0 += 64) {
    int p = p0 + lane;
    bool m = (ti[p] == wid);
    unsigned long long mask = __ballot(m);
    if (m) {
      int pos = base + __popcll(mask & ((1ull << lane) - 1ull));
      ptok[wid * NT + pos] = p >> 1;
      ptk[wid * NT + pos] = p;
      pw[wid * NT + pos] = tw[p];
    }
    base += __popcll(mask);
  }
}

// out[c][r] = bf16(in[r][c]) per expert slice (R,C multiples of 32)
__global__ __launch_bounds__(256) void k_transpose_cvt(const float* __restrict__ in,
                                                       unsigned short* __restrict__ out,
                                                       int R, int C) {
  __shared__ float tile[32][33];
  int e = blockIdx.z;
  const float* ip = in + (size_t)e * R * C;
  unsigned short* op = out + (size_t)e * R * C;
  int tx = threadIdx.x & 31, ty = threadIdx.x >> 5;
  int c = blockIdx.x * 32 + tx;
  int r0 = blockIdx.y * 32;
#pragma unroll
  for (int i = 0; i < 4; i++) tile[ty + i * 8][tx] = ip[(size_t)(r0 + ty + i * 8) * C + c];
  __syncthreads();
  int r = r0 + tx;
#pragma unroll
  for (int i = 0; i < 4; i++)
    op[(size_t)(blockIdx.x * 32 + ty + i * 8) * R + r] = f2bf(tile[tx][ty + i * 8]);
}

__global__ __launch_bounds__(256) void k_cvt(const float* __restrict__ in,
                                             unsigned short* __restrict__ out, int n4) {
  int i = blockIdx.x * blockDim.x + threadIdx.x;
  if (i < n4) {
    float4 v = ((const float4*)in)[i];
    ushort4 o; o.x = f2bf(v.x); o.y = f2bf(v.y); o.z = f2bf(v.z); o.w = f2bf(v.w);
    ((ushort4*)out)[i] = o;
  }
}

#define BM 128
#define BN 128
#define BK 32
#define LDSP 40   // padded k-stride (bf16 elems): 80B rows -> conflict-free b128 frags

// GEMM1: hpre[offs[e]+pos][:] = gathered_x[tok] @ w1T[e]^T + b1[e]
__global__ __launch_bounds__(256) void k_gemm1(
    const unsigned short* __restrict__ xbf,   // [NT][DIMX] bf16
    const unsigned short* __restrict__ w1t,   // [E][HID][DIMX] bf16 (n-major, k-contig)
    const float* __restrict__ bias1,          // [E][HID]
    const int* __restrict__ cnt, const int* __restrict__ offs,
    const int* __restrict__ ptok,
    unsigned short* __restrict__ hpre)        // [NPAIR][HID] bf16
{
  int e = blockIdx.z;
  int n_e = cnt[e];
  int row0 = blockIdx.y * BM;
  if (row0 >= n_e) return;
  int col0 = blockIdx.x * BN;
  int offs_e = offs[e];

  __shared__ __align__(16) unsigned short As[BM][LDSP];
  __shared__ __align__(16) unsigned short Bs[BN][LDSP];

  int tid = threadIdx.x;
  int lane = tid & 63, wid = tid >> 6;
  int wr = wid >> 1, wc = wid & 1;
  int quad = lane >> 4, m16 = lane & 15;

  int r0 = tid >> 2, kc = tid & 3;
  int r1 = r0 + 64;
  int g0 = row0 + r0, g1 = row0 + r1;
  int t0 = (g0 < n_e) ? ptok[e * NT + g0] : 0;
  int t1 = (g1 < n_e) ? ptok[e * NT + g1] : 0;
  const unsigned short* a0p = xbf + (size_t)t0 * DIMX + kc * 8;
  const unsigned short* a1p = xbf + (size_t)t1 * DIMX + kc * 8;
  const unsigned short* bb = w1t + (size_t)e * HID * DIMX;
  const unsigned short* b0p = bb + (size_t)(col0 + r0) * DIMX + kc * 8;
  const unsigned short* b1p = bb + (size_t)(col0 + r1) * DIMX + kc * 8;

  f32x4 acc[4][4];
#pragma unroll
  for (int i = 0; i < 4; i++)
#pragma unroll
    for (int j = 0; j < 4; j++) acc[i][j] = (f32x4)(0.f);

  for (int k0 = 0; k0 < DIMX; k0 += BK) {
    __syncthreads();
    *(int4*)&As[r0][kc * 8] = *(const int4*)(a0p + k0);
    *(int4*)&As[r1][kc * 8] = *(const int4*)(a1p + k0);
    *(int4*)&Bs[r0][kc * 8] = *(const int4*)(b0p + k0);
    *(int4*)&Bs[r1][kc * 8] = *(const int4*)(b1p + k0);
    __syncthreads();
    bf16x8 af[4], bfr[4];
#pragma unroll
    for (int i = 0; i < 4; i++) af[i]  = *(const bf16x8*)&As[wr * 64 + i * 16 + m16][quad * 8];
#pragma unroll
    for (int i = 0; i < 4; i++) bfr[i] = *(const bf16x8*)&Bs[wc * 64 + i * 16 + m16][quad * 8];
#pragma unroll
    for (int i = 0; i < 4; i++)
#pragma unroll
      for (int j = 0; j < 4; j++)
        acc[i][j] = __builtin_amdgcn_mfma_f32_16x16x32_bf16(af[i], bfr[j], acc[i][j], 0, 0, 0);
  }

#pragma unroll
  for (int i = 0; i < 4; i++) {
#pragma unroll
    for (int r = 0; r < 4; r++) {
      int rl = wr * 64 + i * 16 + quad * 4 + r;
      int g = row0 + rl;
      if (g < n_e) {
        size_t rowbase = (size_t)(offs_e + g) * HID;
#pragma unroll
        for (int j = 0; j < 4; j++) {
          int colg = col0 + wc * 64 + j * 16 + m16;
          float val = acc[i][j][r] + bias1[e * HID + colg];
          hpre[rowbase + colg] = f2bf(val);
        }
      }
    }
  }
}

// in-place row LayerNorm + exact GELU over HID
__global__ __launch_bounds__(256) void k_ln_gelu(unsigned short* __restrict__ h,
                                                 const float* __restrict__ g1,
                                                 const float* __restrict__ bb1,
                                                 const int* __restrict__ offs) {
  __shared__ float sbuf[4];
  int row = blockIdx.x;
  int tid = threadIdx.x;
  int e = 0;
#pragma unroll
  for (int i = 1; i < NE; i++) if (row >= offs[i]) e = i;
  unsigned short* p = h + (size_t)row * HID;
  float v[8];
#pragma unroll
  for (int i = 0; i < 8; i++) v[i] = bf2f(p[tid + i * 256]);
  float s = 0.f;
#pragma unroll
  for (int i = 0; i < 8; i++) s += v[i];
#pragma unroll
  for (int off = 32; off > 0; off >>= 1) s += __shfl_xor(s, off);
  if ((tid & 63) == 0) sbuf[tid >> 6] = s;
  __syncthreads();
  float mean = (sbuf[0] + sbuf[1] + sbuf[2] + sbuf[3]) * (1.f / HID);
  float sq = 0.f;
#pragma unroll
  for (int i = 0; i < 8; i++) { float d = v[i] - mean; sq += d * d; }
#pragma unroll
  for (int off = 32; off > 0; off >>= 1) sq += __shfl_xor(sq, off);
  __syncthreads();
  if ((tid & 63) == 0) sbuf[tid >> 6] = sq;
  __syncthreads();
  float var = (sbuf[0] + sbuf[1] + sbuf[2] + sbuf[3]) * (1.f / HID);
  float rstd = rsqrtf(var + 1e-5f);
#pragma unroll
  for (int i = 0; i < 8; i++) {
    int d = tid + i * 256;
    float xn = (v[i] - mean) * rstd * g1[(size_t)e * HID + d] + bb1[(size_t)e * HID + d];
    float ge = 0.5f * xn * (1.f + erff(xn * 0.7071067811865476f));
    p[d] = f2bf(ge);
  }
}

// GEMM2: ybuf[tk] = (h_row @ w2T[e]^T + b2[e]) * gate_weight
__global__ __launch_bounds__(256) void k_gemm2(
    const unsigned short* __restrict__ hb,    // [NPAIR][HID] bf16
    const unsigned short* __restrict__ w2t,   // [E][DIMX][HID] bf16
    const float* __restrict__ bias2,          // [E][DIMX]
    const int* __restrict__ cnt, const int* __restrict__ offs,
    const int* __restrict__ ptk, const float* __restrict__ pw,
    float* __restrict__ ybuf)                 // [NPAIR][DIMX] f32
{
  int e = blockIdx.z;
  int n_e = cnt[e];
  int row0 = blockIdx.y * BM;
  if (row0 >= n_e) return;
  int col0 = blockIdx.x * BN;
  int offs_e = offs[e];

  __shared__ __align__(16) unsigned short As[BM][LDSP];
  __shared__ __align__(16) unsigned short Bs[BN][LDSP];

  int tid = threadIdx.x;
  int lane = tid & 63, wid = tid >> 6;
  int wr = wid >> 1, wc = wid & 1;
  int quad = lane >> 4, m16 = lane & 15;

  int r0 = tid >> 2, kc = tid & 3;
  int r1 = r0 + 64;
  int g0 = row0 + r0; if (g0 >= n_e) g0 = 0;
  int g1 = row0 + r1; if (g1 >= n_e) g1 = 0;
  const unsigned short* a0p = hb + (size_t)(offs_e + g0) * HID + kc * 8;
  const unsigned short* a1p = hb + (size_t)(offs_e + g1) * HID + kc * 8;
  const unsigned short* bb = w2t + (size_t)e * DIMX * HID;
  const unsigned short* b0p = bb + (size_t)(col0 + r0) * HID + kc * 8;
  const unsigned short* b1p = bb + (size_t)(col0 + r1) * HID + kc * 8;

  f32x4 acc[4][4];
#pragma unroll
  for (int i = 0; i < 4; i++)
#pragma unroll
    for (int j = 0; j < 4; j++) acc[i][j] = (f32x4)(0.f);

  for (int k0 = 0; k0 < HID; k0 += BK) {
    __syncthreads();
    *(int4*)&As[r0][kc * 8] = *(const int4*)(a0p + k0);
    *(int4*)&As[r1][kc * 8] = *(const int4*)(a1p + k0);
    *(int4*)&Bs[r0][kc * 8] = *(const int4*)(b0p + k0);
    *(int4*)&Bs[r1][kc * 8] = *(const int4*)(b1p + k0);
    __syncthreads();
    bf16x8 af[4], bfr[4];
#pragma unroll
    for (int i = 0; i < 4; i++) af[i]  = *(const bf16x8*)&As[wr * 64 + i * 16 + m16][quad * 8];
#pragma unroll
    for (int i = 0; i < 4; i++) bfr[i] = *(const bf16x8*)&Bs[wc * 64 + i * 16 + m16][quad * 8];
#pragma unroll
    for (int i = 0; i < 4; i++)
#pragma unroll
      for (int j = 0; j < 4; j++)
        acc[i][j] = __builtin_amdgcn_mfma_f32_16x16x32_bf16(af[i], bfr[j], acc[i][j], 0, 0, 0);
  }

#pragma unroll
  for (int i = 0; i < 4; i++) {
#pragma unroll
    for (int r = 0; r < 4; r++) {
      int rl = wr * 64 + i * 16 + quad * 4 + r;
      int g = row0 + rl;
      if (g < n_e) {
        int pi = e * NT + g;
        float w = pw[pi];
        size_t obase = (size_t)ptk[pi] * DIMX;
#pragma unroll
        for (int j = 0; j < 4; j++) {
          int colg = col0 + wc * 64 + j * 16 + m16;
          ybuf[obase + colg] = (acc[i][j][r] + bias2[e * DIMX + colg]) * w;
        }
      }
    }
  }
}

// out = LN(y_slot0 + y_slot1 + x) with ln_g/ln_b
__global__ __launch_bounds__(256) void k_final(const float* __restrict__ yb,
                                               const float* __restrict__ x,
                                               const float* __restrict__ lg,
                                               const float* __restrict__ lb,
                                               float* __restrict__ out) {
  __shared__ float sbuf[4];
  int t = blockIdx.x, tid = threadIdx.x;
  const float4* y0 = (const float4*)(yb + (size_t)t * 2 * DIMX);
  const float4* y1 = y0 + DIMX / 4;
  const float4* x4 = (const float4*)(x + (size_t)t * DIMX);
  float4 a = y0[tid], b = y1[tid], c = x4[tid];
  float4 v; v.x = a.x + b.x + c.x; v.y = a.y + b.y + c.y;
  v.z = a.z + b.z + c.z; v.w = a.w + b.w + c.w;
  float s = v.x + v.y + v.z + v.w;
#pragma unroll
  for (int off = 32; off > 0; off >>= 1) s += __shfl_xor(s, off);
  if ((tid & 63) == 0) sbuf[tid >> 6] = s;
  __syncthreads();
  float mean = (sbuf[0] + sbuf[1] + sbuf[2] + sbuf[3]) * (1.f / DIMX);
  float dx = v.x - mean, dy = v.y - mean, dz = v.z - mean, dw = v.w - mean;
  float sq = dx * dx + dy * dy + dz * dz + dw * dw;
#pragma unroll
  for (int off = 32; off > 0; off >>= 1) sq += __shfl_xor(sq, off);
  __syncthreads();
  if ((tid & 63) == 0) sbuf[tid >> 6] = sq;
  __syncthreads();
  float var = (sbuf[0] + sbuf[1] + sbuf[2] + sbuf[3]) * (1.f / DIMX);
  float rstd = rsqrtf(var + 1e-5f);
  float4 g = ((const float4*)lg)[tid], bb = ((const float4*)lb)[tid];
  float4 o; o.x = dx * rstd * g.x + bb.x; o.y = dy * rstd * g.y + bb.y;
  o.z = dz * rstd * g.z + bb.z; o.w = dw * rstd * g.w + bb.w;
  ((float4*)(out + (size_t)t * DIMX))[tid] = o;
}

extern "C" void kernel_launch(void* const* d_in, const int* in_sizes, int n_in,
                              void* d_out, int out_size, void* d_ws, size_t ws_size,
                              hipStream_t stream) {
  const float* x     = (const float*)d_in[0];
  const float* gw    = (const float*)d_in[1];
  const float* w1    = (const float*)d_in[2];
  const float* b1    = (const float*)d_in[3];
  const float* ln1g  = (const float*)d_in[4];
  const float* ln1b  = (const float*)d_in[5];
  const float* w2    = (const float*)d_in[6];
  const float* b2    = (const float*)d_in[7];
  const float* lng   = (const float*)d_in[8];
  const float* lnb   = (const float*)d_in[9];
  float* out = (float*)d_out;

  char* ws = (char*)d_ws;
  int* cnt  = (int*)(ws + O_CNT);
  int* offs = (int*)(ws + O_OFFS);
  int* ptok = (int*)(ws + O_TOK);
  int* ptk  = (int*)(ws + O_TK);
  float* pw = (float*)(ws + O_PW);
  int* ti   = (int*)(ws + O_TI);
  float* tw = (float*)(ws + O_TW);
  unsigned short* xbf = (unsigned short*)(ws + O_XBF);
  unsigned short* w1t = (unsigned short*)(ws + O_W1T);
  unsigned short* w2t = (unsigned short*)(ws + O_W2T);
  unsigned short* hpre = (unsigned short*)(ws + O_H);
  float* ybuf = (float*)(ws + O_Y);

  hipLaunchKernelGGL(k_gate_top2, dim3(NT), dim3(64), 0, stream, x, gw, ti, tw);
  hipLaunchKernelGGL(k_build, dim3(1), dim3(512), 0, stream, ti, tw, cnt, offs, ptok, ptk, pw);
  // bf16 conversions / transposes
  hipLaunchKernelGGL(k_cvt, dim3(NT * DIMX / 4 / 256), dim3(256), 0, stream, x, xbf, NT * DIMX / 4);
  hipLaunchKernelGGL(k_transpose_cvt, dim3(HID / 32, DIMX / 32, NE), dim3(256), 0, stream,
                     w1, w1t, DIMX, HID);
  hipLaunchKernelGGL(k_transpose_cvt, dim3(DIMX / 32, HID / 32, NE), dim3(256), 0, stream,
                     w2, w2t, HID, DIMX);
  // expert FFN
  hipLaunchKernelGGL(k_gemm1, dim3(HID / BN, NT / BM, NE), dim3(256), 0, stream,
                     xbf, w1t, b1, cnt, offs, ptok, hpre);
  hipLaunchKernelGGL(k_ln_gelu, dim3(NPAIR), dim3(256), 0, stream, hpre, ln1g, ln1b, offs);
  hipLaunchKernelGGL(k_gemm2, dim3(DIMX / BN, NT / BM, NE), dim3(256), 0, stream,
                     hpre, w2t, b2, cnt, offs, ptk, pw, ybuf);
  hipLaunchKernelGGL(k_final, dim3(NT), dim3(256), 0, stream, ybuf, x, lng, lnb, out);
}

// Round 3
// 415.799 us; speedup vs baseline: 1.1569x; 1.0498x over previous
//
#include <hip/hip_runtime.h>
#include <hip/hip_bf16.h>

#define DIMX 1024
#define HID  2048
#define NE   8
#define NT   4096
#define NPAIR 8192

typedef __attribute__((ext_vector_type(8))) __bf16 bf16x8;
typedef __attribute__((ext_vector_type(4))) float f32x4;

__device__ inline unsigned short f2bf(float f) {
  union { float f; unsigned u; } v; v.f = f;
  unsigned r = v.u + 0x7FFFu + ((v.u >> 16) & 1u);
  return (unsigned short)(r >> 16);
}
__device__ inline float bf2f(unsigned short h) {
  union { unsigned u; float f; } v; v.u = ((unsigned)h) << 16;
  return v.f;
}

// async global->LDS, 16B per lane; LDS dest is wave-uniform base + lane*16
__device__ __forceinline__ void gload_lds16(const unsigned short* g, unsigned short* l) {
  __builtin_amdgcn_global_load_lds(
      (const __attribute__((address_space(1))) unsigned int*)g,
      (__attribute__((address_space(3))) unsigned int*)l, 16, 0, 0);
}

// ---------------- workspace layout (bytes) ----------------
#define O_CNT   0u
#define O_OFFS  256u
#define O_TOK   1024u
#define O_TK    (O_TOK + 131072u)
#define O_PW    (O_TK + 131072u)
#define O_TI    (O_PW + 131072u)
#define O_TW    (O_TI + 32768u)
#define O_XBF   524288u
#define O_W1T   16777216u
#define O_W2T   50331648u
#define O_H     83886080u
#define O_Y     117440512u

__global__ __launch_bounds__(64) void k_gate_top2(const float* __restrict__ x,
                                                  const float* __restrict__ gw,
                                                  int* __restrict__ ti,
                                                  float* __restrict__ tw) {
  int t = blockIdx.x;
  int lane = threadIdx.x;
  float p[NE];
#pragma unroll
  for (int e = 0; e < NE; e++) p[e] = 0.f;
  const float* xr = x + (size_t)t * DIMX;
  for (int j = 0; j < DIMX / 64; j++) {
    int d = lane + j * 64;
    float xv = xr[d];
    const float4* g4 = (const float4*)(gw + (size_t)d * NE);
    float4 a = g4[0], b = g4[1];
    p[0] += xv * a.x; p[1] += xv * a.y; p[2] += xv * a.z; p[3] += xv * a.w;
    p[4] += xv * b.x; p[5] += xv * b.y; p[6] += xv * b.z; p[7] += xv * b.w;
  }
#pragma unroll
  for (int e = 0; e < NE; e++)
#pragma unroll
    for (int off = 32; off > 0; off >>= 1) p[e] += __shfl_xor(p[e], off);
  if (lane == 0) {
    int ia = 0; float va = p[0];
#pragma unroll
    for (int e = 1; e < NE; e++) if (p[e] > va) { va = p[e]; ia = e; }
    int ib = -1; float vb = -3.0e38f;
#pragma unroll
    for (int e = 0; e < NE; e++) { if (e == ia) continue; if (p[e] > vb) { vb = p[e]; ib = e; } }
    float w0 = 1.f / (1.f + expf(vb - va));
    ti[t * 2] = ia;     tw[t * 2] = w0;
    ti[t * 2 + 1] = ib; tw[t * 2 + 1] = 1.f - w0;
  }
}

// single block, 8 waves (one per expert): deterministic compaction, no atomics
__global__ __launch_bounds__(512) void k_build(const int* __restrict__ ti,
                                               const float* __restrict__ tw,
                                               int* __restrict__ cnt, int* __restrict__ offs,
                                               int* __restrict__ ptok, int* __restrict__ ptk,
                                               float* __restrict__ pw) {
  __shared__ int scnt[NE];
  __shared__ int soffs[NE + 1];
  int wid = threadIdx.x >> 6;
  int lane = threadIdx.x & 63;
  int c = 0;
  for (int p = lane; p < NPAIR; p += 64) c += (ti[p] == wid) ? 1 : 0;
#pragma unroll
  for (int off = 32; off > 0; off >>= 1) c += __shfl_xor(c, off);
  if (lane == 0) scnt[wid] = c;
  __syncthreads();
  if (threadIdx.x == 0) {
    int s = 0;
    for (int e = 0; e < NE; e++) { soffs[e] = s; s += scnt[e]; }
    soffs[NE] = s;
  }
  __syncthreads();
  if (threadIdx.x < NE) {
    cnt[threadIdx.x] = scnt[threadIdx.x];
    offs[threadIdx.x] = soffs[threadIdx.x];
  }
  if (threadIdx.x == 0) offs[NE] = soffs[NE];
  int base = 0;
  for (int p0 = 0; p0 < NPAIR; p0 += 64) {
    int p = p0 + lane;
    bool m = (ti[p] == wid);
    unsigned long long mask = __ballot(m);
    if (m) {
      int pos = base + __popcll(mask & ((1ull << lane) - 1ull));
      ptok[wid * NT + pos] = p >> 1;
      ptk[wid * NT + pos] = p;
      pw[wid * NT + pos] = tw[p];
    }
    base += __popcll(mask);
  }
}

__global__ __launch_bounds__(256) void k_transpose_cvt(const float* __restrict__ in,
                                                       unsigned short* __restrict__ out,
                                                       int R, int C) {
  __shared__ float tile[32][33];
  int e = blockIdx.z;
  const float* ip = in + (size_t)e * R * C;
  unsigned short* op = out + (size_t)e * R * C;
  int tx = threadIdx.x & 31, ty = threadIdx.x >> 5;
  int c = blockIdx.x * 32 + tx;
  int r0 = blockIdx.y * 32;
#pragma unroll
  for (int i = 0; i < 4; i++) tile[ty + i * 8][tx] = ip[(size_t)(r0 + ty + i * 8) * C + c];
  __syncthreads();
  int r = r0 + tx;
#pragma unroll
  for (int i = 0; i < 4; i++)
    op[(size_t)(blockIdx.x * 32 + ty + i * 8) * R + r] = f2bf(tile[tx][ty + i * 8]);
}

__global__ __launch_bounds__(256) void k_cvt(const float* __restrict__ in,
                                             unsigned short* __restrict__ out, int n4) {
  int i = blockIdx.x * blockDim.x + threadIdx.x;
  if (i < n4) {
    float4 v = ((const float4*)in)[i];
    ushort4 o; o.x = f2bf(v.x); o.y = f2bf(v.y); o.z = f2bf(v.z); o.w = f2bf(v.w);
    ((ushort4*)out)[i] = o;
  }
}

#define BM 128
#define BN 128
#define BK 32
// unpadded LDS tiles: required by global_load_lds (wave-uniform base + lane*16)

// GEMM1: hpre[offs[e]+pos][:] = gathered_x[tok] @ w1T[e]^T + b1[e]
__global__ __launch_bounds__(256) void k_gemm1(
    const unsigned short* __restrict__ xbf,   // [NT][DIMX] bf16
    const unsigned short* __restrict__ w1t,   // [E][HID][DIMX] bf16
    const float* __restrict__ bias1,          // [E][HID]
    const int* __restrict__ cnt, const int* __restrict__ offs,
    const int* __restrict__ ptok,
    unsigned short* __restrict__ hpre)        // [NPAIR][HID] bf16
{
  int e = blockIdx.z;
  int n_e = cnt[e];
  int row0 = blockIdx.y * BM;
  if (row0 >= n_e) return;
  int col0 = blockIdx.x * BN;
  int offs_e = offs[e];

  __shared__ __align__(16) unsigned short As[BM][BK];
  __shared__ __align__(16) unsigned short Bs[BN][BK];

  int tid = threadIdx.x;
  int lane = tid & 63, wid = tid >> 6;
  int wr = wid >> 1, wc = wid & 1;
  int quad = lane >> 4, m16 = lane & 15;

  // staging: wave w fills rows [w*32, w*32+32): 2 instrs x 16 rows, lane i -> row i/4, chunk i%4
  int i4 = lane >> 2, kc = lane & 3;
  int ga0 = row0 + wid * 32 + i4;      if (ga0 >= n_e) ga0 = n_e - 1;
  int ga1 = row0 + wid * 32 + 16 + i4; if (ga1 >= n_e) ga1 = n_e - 1;
  int t0 = ptok[e * NT + ga0];
  int t1 = ptok[e * NT + ga1];
  const unsigned short* a0p = xbf + (size_t)t0 * DIMX + kc * 8;
  const unsigned short* a1p = xbf + (size_t)t1 * DIMX + kc * 8;
  const unsigned short* bb = w1t + (size_t)e * HID * DIMX;
  const unsigned short* b0p = bb + (size_t)(col0 + wid * 32 + i4) * DIMX + kc * 8;
  const unsigned short* b1p = bb + (size_t)(col0 + wid * 32 + 16 + i4) * DIMX + kc * 8;
  unsigned short* lA0 = &As[wid * 32][0];
  unsigned short* lA1 = &As[wid * 32 + 16][0];
  unsigned short* lB0 = &Bs[wid * 32][0];
  unsigned short* lB1 = &Bs[wid * 32 + 16][0];

  f32x4 acc[4][4];
#pragma unroll
  for (int i = 0; i < 4; i++)
#pragma unroll
    for (int j = 0; j < 4; j++) acc[i][j] = (f32x4)(0.f);

  for (int k0 = 0; k0 < DIMX; k0 += BK) {
    __syncthreads();
    gload_lds16(a0p + k0, lA0);
    gload_lds16(a1p + k0, lA1);
    gload_lds16(b0p + k0, lB0);
    gload_lds16(b1p + k0, lB1);
    __syncthreads();
    bf16x8 af[4], bfr[4];
#pragma unroll
    for (int i = 0; i < 4; i++) af[i]  = *(const bf16x8*)&As[wr * 64 + i * 16 + m16][quad * 8];
#pragma unroll
    for (int i = 0; i < 4; i++) bfr[i] = *(const bf16x8*)&Bs[wc * 64 + i * 16 + m16][quad * 8];
#pragma unroll
    for (int i = 0; i < 4; i++)
#pragma unroll
      for (int j = 0; j < 4; j++)
        acc[i][j] = __builtin_amdgcn_mfma_f32_16x16x32_bf16(af[i], bfr[j], acc[i][j], 0, 0, 0);
  }

#pragma unroll
  for (int i = 0; i < 4; i++) {
#pragma unroll
    for (int r = 0; r < 4; r++) {
      int rl = wr * 64 + i * 16 + quad * 4 + r;
      int g = row0 + rl;
      if (g < n_e) {
        size_t rowbase = (size_t)(offs_e + g) * HID;
#pragma unroll
        for (int j = 0; j < 4; j++) {
          int colg = col0 + wc * 64 + j * 16 + m16;
          float val = acc[i][j][r] + bias1[e * HID + colg];
          hpre[rowbase + colg] = f2bf(val);
        }
      }
    }
  }
}

// in-place row LayerNorm + exact GELU over HID
__global__ __launch_bounds__(256) void k_ln_gelu(unsigned short* __restrict__ h,
                                                 const float* __restrict__ g1,
                                                 const float* __restrict__ bb1,
                                                 const int* __restrict__ offs) {
  __shared__ float sbuf[4];
  int row = blockIdx.x;
  int tid = threadIdx.x;
  int e = 0;
#pragma unroll
  for (int i = 1; i < NE; i++) if (row >= offs[i]) e = i;
  unsigned short* p = h + (size_t)row * HID;
  float v[8];
#pragma unroll
  for (int i = 0; i < 8; i++) v[i] = bf2f(p[tid + i * 256]);
  float s = 0.f;
#pragma unroll
  for (int i = 0; i < 8; i++) s += v[i];
#pragma unroll
  for (int off = 32; off > 0; off >>= 1) s += __shfl_xor(s, off);
  if ((tid & 63) == 0) sbuf[tid >> 6] = s;
  __syncthreads();
  float mean = (sbuf[0] + sbuf[1] + sbuf[2] + sbuf[3]) * (1.f / HID);
  float sq = 0.f;
#pragma unroll
  for (int i = 0; i < 8; i++) { float d = v[i] - mean; sq += d * d; }
#pragma unroll
  for (int off = 32; off > 0; off >>= 1) sq += __shfl_xor(sq, off);
  __syncthreads();
  if ((tid & 63) == 0) sbuf[tid >> 6] = sq;
  __syncthreads();
  float var = (sbuf[0] + sbuf[1] + sbuf[2] + sbuf[3]) * (1.f / HID);
  float rstd = rsqrtf(var + 1e-5f);
#pragma unroll
  for (int i = 0; i < 8; i++) {
    int d = tid + i * 256;
    float xn = (v[i] - mean) * rstd * g1[(size_t)e * HID + d] + bb1[(size_t)e * HID + d];
    float ge = 0.5f * xn * (1.f + erff(xn * 0.7071067811865476f));
    p[d] = f2bf(ge);
  }
}

// GEMM2: ybuf[tk] = (h_row @ w2T[e]^T + b2[e]) * gate_weight
__global__ __launch_bounds__(256) void k_gemm2(
    const unsigned short* __restrict__ hb,    // [NPAIR][HID] bf16
    const unsigned short* __restrict__ w2t,   // [E][DIMX][HID] bf16
    const float* __restrict__ bias2,          // [E][DIMX]
    const int* __restrict__ cnt, const int* __restrict__ offs,
    const int* __restrict__ ptk, const float* __restrict__ pw,
    float* __restrict__ ybuf)                 // [NPAIR][DIMX] f32
{
  int e = blockIdx.z;
  int n_e = cnt[e];
  int row0 = blockIdx.y * BM;
  if (row0 >= n_e) return;
  int col0 = blockIdx.x * BN;
  int offs_e = offs[e];

  __shared__ __align__(16) unsigned short As[BM][BK];
  __shared__ __align__(16) unsigned short Bs[BN][BK];

  int tid = threadIdx.x;
  int lane = tid & 63, wid = tid >> 6;
  int wr = wid >> 1, wc = wid & 1;
  int quad = lane >> 4, m16 = lane & 15;

  int i4 = lane >> 2, kc = lane & 3;
  int ga0 = row0 + wid * 32 + i4;      if (ga0 >= n_e) ga0 = n_e - 1;
  int ga1 = row0 + wid * 32 + 16 + i4; if (ga1 >= n_e) ga1 = n_e - 1;
  const unsigned short* a0p = hb + (size_t)(offs_e + ga0) * HID + kc * 8;
  const unsigned short* a1p = hb + (size_t)(offs_e + ga1) * HID + kc * 8;
  const unsigned short* bb = w2t + (size_t)e * DIMX * HID;
  const unsigned short* b0p = bb + (size_t)(col0 + wid * 32 + i4) * HID + kc * 8;
  const unsigned short* b1p = bb + (size_t)(col0 + wid * 32 + 16 + i4) * HID + kc * 8;
  unsigned short* lA0 = &As[wid * 32][0];
  unsigned short* lA1 = &As[wid * 32 + 16][0];
  unsigned short* lB0 = &Bs[wid * 32][0];
  unsigned short* lB1 = &Bs[wid * 32 + 16][0];

  f32x4 acc[4][4];
#pragma unroll
  for (int i = 0; i < 4; i++)
#pragma unroll
    for (int j = 0; j < 4; j++) acc[i][j] = (f32x4)(0.f);

  for (int k0 = 0; k0 < HID; k0 += BK) {
    __syncthreads();
    gload_lds16(a0p + k0, lA0);
    gload_lds16(a1p + k0, lA1);
    gload_lds16(b0p + k0, lB0);
    gload_lds16(b1p + k0, lB1);
    __syncthreads();
    bf16x8 af[4], bfr[4];
#pragma unroll
    for (int i = 0; i < 4; i++) af[i]  = *(const bf16x8*)&As[wr * 64 + i * 16 + m16][quad * 8];
#pragma unroll
    for (int i = 0; i < 4; i++) bfr[i] = *(const bf16x8*)&Bs[wc * 64 + i * 16 + m16][quad * 8];
#pragma unroll
    for (int i = 0; i < 4; i++)
#pragma unroll
      for (int j = 0; j < 4; j++)
        acc[i][j] = __builtin_amdgcn_mfma_f32_16x16x32_bf16(af[i], bfr[j], acc[i][j], 0, 0, 0);
  }

#pragma unroll
  for (int i = 0; i < 4; i++) {
#pragma unroll
    for (int r = 0; r < 4; r++) {
      int rl = wr * 64 + i * 16 + quad * 4 + r;
      int g = row0 + rl;
      if (g < n_e) {
        int pi = e * NT + g;
        float w = pw[pi];
        size_t obase = (size_t)ptk[pi] * DIMX;
#pragma unroll
        for (int j = 0; j < 4; j++) {
          int colg = col0 + wc * 64 + j * 16 + m16;
          ybuf[obase + colg] = (acc[i][j][r] + bias2[e * DIMX + colg]) * w;
        }
      }
    }
  }
}

// out = LN(y_slot0 + y_slot1 + x)
__global__ __launch_bounds__(256) void k_final(const float* __restrict__ yb,
                                               const float* __restrict__ x,
                                               const float* __restrict__ lg,
                                               const float* __restrict__ lb,
                                               float* __restrict__ out) {
  __shared__ float sbuf[4];
  int t = blockIdx.x, tid = threadIdx.x;
  const float4* y0 = (const float4*)(yb + (size_t)t * 2 * DIMX);
  const float4* y1 = y0 + DIMX / 4;
  const float4* x4 = (const float4*)(x + (size_t)t * DIMX);
  float4 a = y0[tid], b = y1[tid], c = x4[tid];
  float4 v; v.x = a.x + b.x + c.x; v.y = a.y + b.y + c.y;
  v.z = a.z + b.z + c.z; v.w = a.w + b.w + c.w;
  float s = v.x + v.y + v.z + v.w;
#pragma unroll
  for (int off = 32; off > 0; off >>= 1) s += __shfl_xor(s, off);
  if ((tid & 63) == 0) sbuf[tid >> 6] = s;
  __syncthreads();
  float mean = (sbuf[0] + sbuf[1] + sbuf[2] + sbuf[3]) * (1.f / DIMX);
  float dx = v.x - mean, dy = v.y - mean, dz = v.z - mean, dw = v.w - mean;
  float sq = dx * dx + dy * dy + dz * dz + dw * dw;
#pragma unroll
  for (int off = 32; off > 0; off >>= 1) sq += __shfl_xor(sq, off);
  __syncthreads();
  if ((tid & 63) == 0) sbuf[tid >> 6] = sq;
  __syncthreads();
  float var = (sbuf[0] + sbuf[1] + sbuf[2] + sbuf[3]) * (1.f / DIMX);
  float rstd = rsqrtf(var + 1e-5f);
  float4 g = ((const float4*)lg)[tid], bb = ((const float4*)lb)[tid];
  float4 o; o.x = dx * rstd * g.x + bb.x; o.y = dy * rstd * g.y + bb.y;
  o.z = dz * rstd * g.z + bb.z; o.w = dw * rstd * g.w + bb.w;
  ((float4*)(out + (size_t)t * DIMX))[tid] = o;
}

extern "C" void kernel_launch(void* const* d_in, const int* in_sizes, int n_in,
                              void* d_out, int out_size, void* d_ws, size_t ws_size,
                              hipStream_t stream) {
  const float* x     = (const float*)d_in[0];
  const float* gw    = (const float*)d_in[1];
  const float* w1    = (const float*)d_in[2];
  const float* b1    = (const float*)d_in[3];
  const float* ln1g  = (const float*)d_in[4];
  const float* ln1b  = (const float*)d_in[5];
  const float* w2    = (const float*)d_in[6];
  const float* b2    = (const float*)d_in[7];
  const float* lng   = (const float*)d_in[8];
  const float* lnb   = (const float*)d_in[9];
  float* out = (float*)d_out;

  char* ws = (char*)d_ws;
  int* cnt  = (int*)(ws + O_CNT);
  int* offs = (int*)(ws + O_OFFS);
  int* ptok = (int*)(ws + O_TOK);
  int* ptk  = (int*)(ws + O_TK);
  float* pw = (float*)(ws + O_PW);
  int* ti   = (int*)(ws + O_TI);
  float* tw = (float*)(ws + O_TW);
  unsigned short* xbf = (unsigned short*)(ws + O_XBF);
  unsigned short* w1t = (unsigned short*)(ws + O_W1T);
  unsigned short* w2t = (unsigned short*)(ws + O_W2T);
  unsigned short* hpre = (unsigned short*)(ws + O_H);
  float* ybuf = (float*)(ws + O_Y);

  hipLaunchKernelGGL(k_gate_top2, dim3(NT), dim3(64), 0, stream, x, gw, ti, tw);
  hipLaunchKernelGGL(k_build, dim3(1), dim3(512), 0, stream, ti, tw, cnt, offs, ptok, ptk, pw);
  hipLaunchKernelGGL(k_cvt, dim3(NT * DIMX / 4 / 256), dim3(256), 0, stream, x, xbf, NT * DIMX / 4);
  hipLaunchKernelGGL(k_transpose_cvt, dim3(HID / 32, DIMX / 32, NE), dim3(256), 0, stream,
                     w1, w1t, DIMX, HID);
  hipLaunchKernelGGL(k_transpose_cvt, dim3(DIMX / 32, HID / 32, NE), dim3(256), 0, stream,
                     w2, w2t, HID, DIMX);
  hipLaunchKernelGGL(k_gemm1, dim3(HID / BN, NT / BM, NE), dim3(256), 0, stream,
                     xbf, w1t, b1, cnt, offs, ptok, hpre);
  hipLaunchKernelGGL(k_ln_gelu, dim3(NPAIR), dim3(256), 0, stream, hpre, ln1g, ln1b, offs);
  hipLaunchKernelGGL(k_gemm2, dim3(DIMX / BN, NT / BM, NE), dim3(256), 0, stream,
                     hpre, w2t, b2, cnt, offs, ptk, pw, ybuf);
  hipLaunchKernelGGL(k_final, dim3(NT), dim3(256), 0, stream, ybuf, x, lng, lnb, out);
}

// Round 4
// 401.926 us; speedup vs baseline: 1.1968x; 1.0345x over previous
//
#include <hip/hip_runtime.h>
#include <hip/hip_bf16.h>

#define DIMX 1024
#define HID  2048
#define NE   8
#define NT   4096
#define NPAIR 8192
#define MAXSTRIP 72

typedef __attribute__((ext_vector_type(8))) __bf16 bf16x8;
typedef __attribute__((ext_vector_type(4))) float f32x4;

__device__ inline unsigned short f2bf(float f) {
  union { float f; unsigned u; } v; v.f = f;
  unsigned r = v.u + 0x7FFFu + ((v.u >> 16) & 1u);
  return (unsigned short)(r >> 16);
}
__device__ inline float bf2f(unsigned short h) {
  union { unsigned u; float f; } v; v.u = ((unsigned)h) << 16;
  return v.f;
}

__device__ __forceinline__ void gload_lds16(const unsigned short* g, unsigned short* l) {
  __builtin_amdgcn_global_load_lds(
      (const __attribute__((address_space(1))) unsigned int*)g,
      (__attribute__((address_space(3))) unsigned int*)l, 16, 0, 0);
}

// ---------------- workspace layout (bytes) ----------------
#define O_CNT   0u
#define O_TOK   1024u
#define O_TK    132096u
#define O_PW    263168u
#define O_TI    394240u
#define O_TW    427008u
#define O_POFF  459776u        // 9 int padded offsets
#define O_SE    459904u        // 72 int strip->expert
#define O_SR0   460416u        // 72 int strip->row0 (within expert)
#define O_XBF   524288u        // 4096*1024 bf16
#define O_W1T   16777216u      // 8*2048*1024 bf16
#define O_W2T   50331648u      // 8*1024*2048 bf16
#define O_H     83886080u      // 9216*2048 bf16 (padded rows)
#define O_Y     121634816u     // 8192*1024 f32
// end ~148 MB

// fused: bf16-convert x row + gate logits + top-2 (one wave per token)
__global__ __launch_bounds__(256) void k_gate_cvt(const float* __restrict__ x,
                                                  const float* __restrict__ gw,
                                                  unsigned short* __restrict__ xbf,
                                                  int* __restrict__ ti,
                                                  float* __restrict__ tw) {
  int t = blockIdx.x * 4 + (threadIdx.x >> 6);
  int lane = threadIdx.x & 63;
  const float4* xr = (const float4*)(x + (size_t)t * DIMX);
  ushort4* xo = (ushort4*)(xbf + (size_t)t * DIMX);
  float p[NE];
#pragma unroll
  for (int e = 0; e < NE; e++) p[e] = 0.f;
#pragma unroll
  for (int j = 0; j < 4; j++) {
    int idx4 = j * 64 + lane;
    float4 v = xr[idx4];
    ushort4 o; o.x = f2bf(v.x); o.y = f2bf(v.y); o.z = f2bf(v.z); o.w = f2bf(v.w);
    xo[idx4] = o;
    const float4* gp = (const float4*)(gw + (size_t)(idx4 * 4) * NE);
    float4 gA = gp[0], gB = gp[1], gC = gp[2], gD = gp[3];
    float4 gE = gp[4], gF = gp[5], gG = gp[6], gH = gp[7];
    p[0] += v.x * gA.x + v.y * gC.x + v.z * gE.x + v.w * gG.x;
    p[1] += v.x * gA.y + v.y * gC.y + v.z * gE.y + v.w * gG.y;
    p[2] += v.x * gA.z + v.y * gC.z + v.z * gE.z + v.w * gG.z;
    p[3] += v.x * gA.w + v.y * gC.w + v.z * gE.w + v.w * gG.w;
    p[4] += v.x * gB.x + v.y * gD.x + v.z * gF.x + v.w * gH.x;
    p[5] += v.x * gB.y + v.y * gD.y + v.z * gF.y + v.w * gH.y;
    p[6] += v.x * gB.z + v.y * gD.z + v.z * gF.z + v.w * gH.z;
    p[7] += v.x * gB.w + v.y * gD.w + v.z * gF.w + v.w * gH.w;
  }
#pragma unroll
  for (int e = 0; e < NE; e++)
#pragma unroll
    for (int off = 32; off > 0; off >>= 1) p[e] += __shfl_xor(p[e], off);
  if (lane == 0) {
    int ia = 0; float va = p[0];
#pragma unroll
    for (int e = 1; e < NE; e++) if (p[e] > va) { va = p[e]; ia = e; }
    int ib = -1; float vb = -3.0e38f;
#pragma unroll
    for (int e = 0; e < NE; e++) { if (e == ia) continue; if (p[e] > vb) { vb = p[e]; ib = e; } }
    float w0 = 1.f / (1.f + expf(vb - va));
    ti[t * 2] = ia;     tw[t * 2] = w0;
    ti[t * 2 + 1] = ib; tw[t * 2 + 1] = 1.f - w0;
  }
}

// single block, LDS-staged ti: counts, padded offsets, strip table, compaction
__global__ __launch_bounds__(512) void k_build(const int* __restrict__ ti,
                                               const float* __restrict__ tw,
                                               int* __restrict__ cnt,
                                               int* __restrict__ poffs,
                                               int* __restrict__ s_e, int* __restrict__ s_r0,
                                               int* __restrict__ ptok, int* __restrict__ ptk,
                                               float* __restrict__ pw) {
  __shared__ int sti[NPAIR];         // 32 KB
  __shared__ int scnt[NE];
  for (int i = threadIdx.x; i < NPAIR; i += 512) sti[i] = ti[i];
  __syncthreads();
  int wid = threadIdx.x >> 6;
  int lane = threadIdx.x & 63;
  int c = 0;
  for (int p = lane; p < NPAIR; p += 64) c += (sti[p] == wid) ? 1 : 0;
#pragma unroll
  for (int off = 32; off > 0; off >>= 1) c += __shfl_xor(c, off);
  if (lane == 0) scnt[wid] = c;
  __syncthreads();
  if (threadIdx.x == 0) {
    int s = 0, pacc = 0;
    for (int e = 0; e < NE; e++) {
      cnt[e] = scnt[e];
      poffs[e] = pacc;
      int ns = (scnt[e] + 127) >> 7;
      for (int k = 0; k < ns; k++) { s_e[s] = e; s_r0[s] = k * 128; s++; }
      pacc += ns * 128;
    }
    poffs[NE] = pacc;
    for (; s < MAXSTRIP; s++) { s_e[s] = -1; s_r0[s] = 0; }
  }
  int base = 0;
  for (int p0 = 0; p0 < NPAIR; p0 += 64) {
    int p = p0 + lane;
    bool m = (sti[p] == wid);
    unsigned long long mask = __ballot(m);
    if (m) {
      int pos = base + __popcll(mask & ((1ull << lane) - 1ull));
      ptok[wid * NT + pos] = p >> 1;
      ptk[wid * NT + pos] = p;
      pw[wid * NT + pos] = tw[p];
    }
    base += __popcll(mask);
  }
}

// 64x64 transpose+convert: out[c][r] = bf16(in[r][c]), per expert slice
__global__ __launch_bounds__(256) void k_transpose_cvt(const float* __restrict__ in,
                                                       unsigned short* __restrict__ out,
                                                       int R, int C) {
  __shared__ float tile[64][73];
  int e = blockIdx.z;
  const float* ip = in + (size_t)e * R * C;
  unsigned short* op = out + (size_t)e * R * C;
  int c0 = blockIdx.x * 64, r0 = blockIdx.y * 64;
  int tx = threadIdx.x & 15, ty = threadIdx.x >> 4;
#pragma unroll
  for (int i = 0; i < 4; i++) {
    int row = ty + i * 16;
    float4 v = *(const float4*)(ip + (size_t)(r0 + row) * C + c0 + tx * 4);
    tile[row][tx * 4] = v.x; tile[row][tx * 4 + 1] = v.y;
    tile[row][tx * 4 + 2] = v.z; tile[row][tx * 4 + 3] = v.w;
  }
  __syncthreads();
  int rx = threadIdx.x & 15, cy = threadIdx.x >> 4;
  int r_off = rx * 4;
#pragma unroll
  for (int i = 0; i < 4; i++) {
    int cc = cy + i * 16;
    ushort4 h;
    h.x = f2bf(tile[r_off][cc]);     h.y = f2bf(tile[r_off + 1][cc]);
    h.z = f2bf(tile[r_off + 2][cc]); h.w = f2bf(tile[r_off + 3][cc]);
    *(ushort4*)(op + (size_t)(c0 + cc) * R + r0 + r_off) = h;
  }
}

#define BM 128
#define BN 128
#define BK 32

// GEMM1: hpre[poffs[e]+g][:] = gathered_x[tok] @ w1T[e]^T + b1[e]
__global__ __launch_bounds__(256) void k_gemm1(
    const unsigned short* __restrict__ xbf,
    const unsigned short* __restrict__ w1t,
    const float* __restrict__ bias1,
    const int* __restrict__ cnt, const int* __restrict__ s_e,
    const int* __restrict__ s_r0, const int* __restrict__ poffs,
    const int* __restrict__ ptok,
    unsigned short* __restrict__ hpre)
{
  int s = blockIdx.y;
  int e = s_e[s];
  if (e < 0) return;
  int r0e = s_r0[s];
  int n_e = cnt[e];
  int pbase = poffs[e];
  int col0 = blockIdx.x * BN;

  __shared__ __align__(16) unsigned short As[BM][BK];
  __shared__ __align__(16) unsigned short Bs[BN][BK];

  int tid = threadIdx.x;
  int lane = tid & 63, wid = tid >> 6;
  int wr = wid >> 1, wc = wid & 1;
  int quad = lane >> 4, m16 = lane & 15;

  int i4 = lane >> 2, kc = lane & 3;
  int ga0 = r0e + wid * 32 + i4;      if (ga0 >= n_e) ga0 = n_e - 1;
  int ga1 = r0e + wid * 32 + 16 + i4; if (ga1 >= n_e) ga1 = n_e - 1;
  int t0 = ptok[e * NT + ga0];
  int t1 = ptok[e * NT + ga1];
  const unsigned short* a0p = xbf + (size_t)t0 * DIMX + kc * 8;
  const unsigned short* a1p = xbf + (size_t)t1 * DIMX + kc * 8;
  const unsigned short* bb = w1t + (size_t)e * HID * DIMX;
  const unsigned short* b0p = bb + (size_t)(col0 + wid * 32 + i4) * DIMX + kc * 8;
  const unsigned short* b1p = bb + (size_t)(col0 + wid * 32 + 16 + i4) * DIMX + kc * 8;
  unsigned short* lA0 = &As[wid * 32][0];
  unsigned short* lA1 = &As[wid * 32 + 16][0];
  unsigned short* lB0 = &Bs[wid * 32][0];
  unsigned short* lB1 = &Bs[wid * 32 + 16][0];

  f32x4 acc[4][4];
#pragma unroll
  for (int i = 0; i < 4; i++)
#pragma unroll
    for (int j = 0; j < 4; j++) acc[i][j] = (f32x4)(0.f);

  for (int k0 = 0; k0 < DIMX; k0 += BK) {
    __syncthreads();
    gload_lds16(a0p + k0, lA0);
    gload_lds16(a1p + k0, lA1);
    gload_lds16(b0p + k0, lB0);
    gload_lds16(b1p + k0, lB1);
    __syncthreads();
    bf16x8 af[4], bfr[4];
#pragma unroll
    for (int i = 0; i < 4; i++) af[i]  = *(const bf16x8*)&As[wr * 64 + i * 16 + m16][quad * 8];
#pragma unroll
    for (int i = 0; i < 4; i++) bfr[i] = *(const bf16x8*)&Bs[wc * 64 + i * 16 + m16][quad * 8];
#pragma unroll
    for (int i = 0; i < 4; i++)
#pragma unroll
      for (int j = 0; j < 4; j++)
        acc[i][j] = __builtin_amdgcn_mfma_f32_16x16x32_bf16(af[i], bfr[j], acc[i][j], 0, 0, 0);
  }

#pragma unroll
  for (int i = 0; i < 4; i++) {
#pragma unroll
    for (int r = 0; r < 4; r++) {
      int g = r0e + wr * 64 + i * 16 + quad * 4 + r;
      if (g < n_e) {
        size_t rowbase = (size_t)(pbase + g) * HID;
#pragma unroll
        for (int j = 0; j < 4; j++) {
          int colg = col0 + wc * 64 + j * 16 + m16;
          float val = acc[i][j][r] + bias1[e * HID + colg];
          hpre[rowbase + colg] = f2bf(val);
        }
      }
    }
  }
}

// in-place row LayerNorm + exact GELU over HID (padded rows)
__global__ __launch_bounds__(256) void k_ln_gelu(unsigned short* __restrict__ h,
                                                 const float* __restrict__ g1,
                                                 const float* __restrict__ bb1,
                                                 const int* __restrict__ s_e) {
  __shared__ float sbuf[4];
  int row = blockIdx.x;
  int e = s_e[row >> 7];
  if (e < 0) return;
  int tid = threadIdx.x;
  unsigned short* p = h + (size_t)row * HID;
  ushort4 u0 = ((const ushort4*)p)[tid * 2];
  ushort4 u1 = ((const ushort4*)p)[tid * 2 + 1];
  float v[8];
  v[0] = bf2f(u0.x); v[1] = bf2f(u0.y); v[2] = bf2f(u0.z); v[3] = bf2f(u0.w);
  v[4] = bf2f(u1.x); v[5] = bf2f(u1.y); v[6] = bf2f(u1.z); v[7] = bf2f(u1.w);
  float s = 0.f;
#pragma unroll
  for (int i = 0; i < 8; i++) s += v[i];
#pragma unroll
  for (int off = 32; off > 0; off >>= 1) s += __shfl_xor(s, off);
  if ((tid & 63) == 0) sbuf[tid >> 6] = s;
  __syncthreads();
  float mean = (sbuf[0] + sbuf[1] + sbuf[2] + sbuf[3]) * (1.f / HID);
  float sq = 0.f;
#pragma unroll
  for (int i = 0; i < 8; i++) { float d = v[i] - mean; sq += d * d; }
#pragma unroll
  for (int off = 32; off > 0; off >>= 1) sq += __shfl_xor(sq, off);
  __syncthreads();
  if ((tid & 63) == 0) sbuf[tid >> 6] = sq;
  __syncthreads();
  float var = (sbuf[0] + sbuf[1] + sbuf[2] + sbuf[3]) * (1.f / HID);
  float rstd = rsqrtf(var + 1e-5f);
  const float4* gg = (const float4*)(g1 + (size_t)e * HID);
  const float4* gb = (const float4*)(bb1 + (size_t)e * HID);
  float4 ga = gg[tid * 2], gbv = gg[tid * 2 + 1];
  float4 ba = gb[tid * 2], bbv = gb[tid * 2 + 1];
  float gn[8] = {ga.x, ga.y, ga.z, ga.w, gbv.x, gbv.y, gbv.z, gbv.w};
  float bn[8] = {ba.x, ba.y, ba.z, ba.w, bbv.x, bbv.y, bbv.z, bbv.w};
  unsigned short o[8];
#pragma unroll
  for (int i = 0; i < 8; i++) {
    float xn = (v[i] - mean) * rstd * gn[i] + bn[i];
    float ge = 0.5f * xn * (1.f + erff(xn * 0.7071067811865476f));
    o[i] = f2bf(ge);
  }
  ushort4 s0 = {o[0], o[1], o[2], o[3]};
  ushort4 s1 = {o[4], o[5], o[6], o[7]};
  ((ushort4*)p)[tid * 2] = s0;
  ((ushort4*)p)[tid * 2 + 1] = s1;
}

// GEMM2: ybuf[ptk] = (h_row @ w2T[e]^T + b2[e]) * gate_weight
__global__ __launch_bounds__(256) void k_gemm2(
    const unsigned short* __restrict__ hb,
    const unsigned short* __restrict__ w2t,
    const float* __restrict__ bias2,
    const int* __restrict__ cnt, const int* __restrict__ s_e,
    const int* __restrict__ s_r0, const int* __restrict__ poffs,
    const int* __restrict__ ptk, const float* __restrict__ pw,
    float* __restrict__ ybuf)
{
  int s = blockIdx.y;
  int e = s_e[s];
  if (e < 0) return;
  int r0e = s_r0[s];
  int n_e = cnt[e];
  int pbase = poffs[e];
  int col0 = blockIdx.x * BN;

  __shared__ __align__(16) unsigned short As[BM][BK];
  __shared__ __align__(16) unsigned short Bs[BN][BK];

  int tid = threadIdx.x;
  int lane = tid & 63, wid = tid >> 6;
  int wr = wid >> 1, wc = wid & 1;
  int quad = lane >> 4, m16 = lane & 15;

  int i4 = lane >> 2, kc = lane & 3;
  int ga0 = r0e + wid * 32 + i4;      if (ga0 >= n_e) ga0 = n_e - 1;
  int ga1 = r0e + wid * 32 + 16 + i4; if (ga1 >= n_e) ga1 = n_e - 1;
  const unsigned short* a0p = hb + (size_t)(pbase + ga0) * HID + kc * 8;
  const unsigned short* a1p = hb + (size_t)(pbase + ga1) * HID + kc * 8;
  const unsigned short* bb = w2t + (size_t)e * DIMX * HID;
  const unsigned short* b0p = bb + (size_t)(col0 + wid * 32 + i4) * HID + kc * 8;
  const unsigned short* b1p = bb + (size_t)(col0 + wid * 32 + 16 + i4) * HID + kc * 8;
  unsigned short* lA0 = &As[wid * 32][0];
  unsigned short* lA1 = &As[wid * 32 + 16][0];
  unsigned short* lB0 = &Bs[wid * 32][0];
  unsigned short* lB1 = &Bs[wid * 32 + 16][0];

  f32x4 acc[4][4];
#pragma unroll
  for (int i = 0; i < 4; i++)
#pragma unroll
    for (int j = 0; j < 4; j++) acc[i][j] = (f32x4)(0.f);

  for (int k0 = 0; k0 < HID; k0 += BK) {
    __syncthreads();
    gload_lds16(a0p + k0, lA0);
    gload_lds16(a1p + k0, lA1);
    gload_lds16(b0p + k0, lB0);
    gload_lds16(b1p + k0, lB1);
    __syncthreads();
    bf16x8 af[4], bfr[4];
#pragma unroll
    for (int i = 0; i < 4; i++) af[i]  = *(const bf16x8*)&As[wr * 64 + i * 16 + m16][quad * 8];
#pragma unroll
    for (int i = 0; i < 4; i++) bfr[i] = *(const bf16x8*)&Bs[wc * 64 + i * 16 + m16][quad * 8];
#pragma unroll
    for (int i = 0; i < 4; i++)
#pragma unroll
      for (int j = 0; j < 4; j++)
        acc[i][j] = __builtin_amdgcn_mfma_f32_16x16x32_bf16(af[i], bfr[j], acc[i][j], 0, 0, 0);
  }

#pragma unroll
  for (int i = 0; i < 4; i++) {
#pragma unroll
    for (int r = 0; r < 4; r++) {
      int g = r0e + wr * 64 + i * 16 + quad * 4 + r;
      if (g < n_e) {
        int pi = e * NT + g;
        float w = pw[pi];
        size_t obase = (size_t)ptk[pi] * DIMX;
#pragma unroll
        for (int j = 0; j < 4; j++) {
          int colg = col0 + wc * 64 + j * 16 + m16;
          ybuf[obase + colg] = (acc[i][j][r] + bias2[e * DIMX + colg]) * w;
        }
      }
    }
  }
}

// out = LN(y_slot0 + y_slot1 + x)
__global__ __launch_bounds__(256) void k_final(const float* __restrict__ yb,
                                               const float* __restrict__ x,
                                               const float* __restrict__ lg,
                                               const float* __restrict__ lb,
                                               float* __restrict__ out) {
  __shared__ float sbuf[4];
  int t = blockIdx.x, tid = threadIdx.x;
  const float4* y0 = (const float4*)(yb + (size_t)t * 2 * DIMX);
  const float4* y1 = y0 + DIMX / 4;
  const float4* x4 = (const float4*)(x + (size_t)t * DIMX);
  float4 a = y0[tid], b = y1[tid], c = x4[tid];
  float4 v; v.x = a.x + b.x + c.x; v.y = a.y + b.y + c.y;
  v.z = a.z + b.z + c.z; v.w = a.w + b.w + c.w;
  float s = v.x + v.y + v.z + v.w;
#pragma unroll
  for (int off = 32; off > 0; off >>= 1) s += __shfl_xor(s, off);
  if ((tid & 63) == 0) sbuf[tid >> 6] = s;
  __syncthreads();
  float mean = (sbuf[0] + sbuf[1] + sbuf[2] + sbuf[3]) * (1.f / DIMX);
  float dx = v.x - mean, dy = v.y - mean, dz = v.z - mean, dw = v.w - mean;
  float sq = dx * dx + dy * dy + dz * dz + dw * dw;
#pragma unroll
  for (int off = 32; off > 0; off >>= 1) sq += __shfl_xor(sq, off);
  __syncthreads();
  if ((tid & 63) == 0) sbuf[tid >> 6] = sq;
  __syncthreads();
  float var = (sbuf[0] + sbuf[1] + sbuf[2] + sbuf[3]) * (1.f / DIMX);
  float rstd = rsqrtf(var + 1e-5f);
  float4 g = ((const float4*)lg)[tid], bb = ((const float4*)lb)[tid];
  float4 o; o.x = dx * rstd * g.x + bb.x; o.y = dy * rstd * g.y + bb.y;
  o.z = dz * rstd * g.z + bb.z; o.w = dw * rstd * g.w + bb.w;
  ((float4*)(out + (size_t)t * DIMX))[tid] = o;
}

extern "C" void kernel_launch(void* const* d_in, const int* in_sizes, int n_in,
                              void* d_out, int out_size, void* d_ws, size_t ws_size,
                              hipStream_t stream) {
  const float* x     = (const float*)d_in[0];
  const float* gw    = (const float*)d_in[1];
  const float* w1    = (const float*)d_in[2];
  const float* b1    = (const float*)d_in[3];
  const float* ln1g  = (const float*)d_in[4];
  const float* ln1b  = (const float*)d_in[5];
  const float* w2    = (const float*)d_in[6];
  const float* b2    = (const float*)d_in[7];
  const float* lng   = (const float*)d_in[8];
  const float* lnb   = (const float*)d_in[9];
  float* out = (float*)d_out;

  char* ws = (char*)d_ws;
  int* cnt   = (int*)(ws + O_CNT);
  int* ptok  = (int*)(ws + O_TOK);
  int* ptk   = (int*)(ws + O_TK);
  float* pw  = (float*)(ws + O_PW);
  int* ti    = (int*)(ws + O_TI);
  float* tw  = (float*)(ws + O_TW);
  int* poffs = (int*)(ws + O_POFF);
  int* s_e   = (int*)(ws + O_SE);
  int* s_r0  = (int*)(ws + O_SR0);
  unsigned short* xbf  = (unsigned short*)(ws + O_XBF);
  unsigned short* w1t  = (unsigned short*)(ws + O_W1T);
  unsigned short* w2t  = (unsigned short*)(ws + O_W2T);
  unsigned short* hpre = (unsigned short*)(ws + O_H);
  float* ybuf = (float*)(ws + O_Y);

  hipLaunchKernelGGL(k_gate_cvt, dim3(NT / 4), dim3(256), 0, stream, x, gw, xbf, ti, tw);
  hipLaunchKernelGGL(k_build, dim3(1), dim3(512), 0, stream, ti, tw, cnt, poffs, s_e, s_r0,
                     ptok, ptk, pw);
  hipLaunchKernelGGL(k_transpose_cvt, dim3(HID / 64, DIMX / 64, NE), dim3(256), 0, stream,
                     w1, w1t, DIMX, HID);
  hipLaunchKernelGGL(k_transpose_cvt, dim3(DIMX / 64, HID / 64, NE), dim3(256), 0, stream,
                     w2, w2t, HID, DIMX);
  hipLaunchKernelGGL(k_gemm1, dim3(HID / BN, MAXSTRIP), dim3(256), 0, stream,
                     xbf, w1t, b1, cnt, s_e, s_r0, poffs, ptok, hpre);
  hipLaunchKernelGGL(k_ln_gelu, dim3(MAXSTRIP * BM), dim3(256), 0, stream, hpre, ln1g, ln1b, s_e);
  hipLaunchKernelGGL(k_gemm2, dim3(DIMX / BN, MAXSTRIP), dim3(256), 0, stream,
                     hpre, w2t, b2, cnt, s_e, s_r0, poffs, ptk, pw, ybuf);
  hipLaunchKernelGGL(k_final, dim3(NT), dim3(256), 0, stream, ybuf, x, lng, lnb, out);
}

// Round 5
// 391.225 us; speedup vs baseline: 1.2296x; 1.0274x over previous
//
#include <hip/hip_runtime.h>
#include <hip/hip_bf16.h>

#define DIMX 1024
#define HID  2048
#define NE   8
#define NT   4096
#define NPAIR 8192
#define MAXSTRIP 72

typedef __attribute__((ext_vector_type(8))) __bf16 bf16x8;
typedef __attribute__((ext_vector_type(4))) float f32x4;

__device__ inline unsigned short f2bf(float f) {
  union { float f; unsigned u; } v; v.f = f;
  unsigned r = v.u + 0x7FFFu + ((v.u >> 16) & 1u);
  return (unsigned short)(r >> 16);
}
__device__ inline float bf2f(unsigned short h) {
  union { unsigned u; float f; } v; v.u = ((unsigned)h) << 16;
  return v.f;
}

__device__ __forceinline__ void gload_lds16(const unsigned short* g, unsigned short* l) {
  __builtin_amdgcn_global_load_lds(
      (const __attribute__((address_space(1))) unsigned int*)g,
      (__attribute__((address_space(3))) unsigned int*)l, 16, 0, 0);
}

// ---------------- workspace layout (bytes) ----------------
#define O_CNT   0u
#define O_TOK   1024u
#define O_TK    132096u
#define O_PW    263168u
#define O_TI    394240u
#define O_TW    427008u
#define O_POFF  459776u
#define O_SE    459904u
#define O_SR0   460416u
#define O_XBF   524288u        // 4096*1024 bf16
#define O_W1T   16777216u      // 8*2048*1024 bf16
#define O_W2T   50331648u      // 8*1024*2048 bf16
#define O_H     83886080u      // 9216*2048 bf16 (padded rows)
#define O_Y     121634816u     // 8192*1024 f32

// fused: bf16-convert x row + gate logits + top-2 (one wave per token)
__global__ __launch_bounds__(256) void k_gate_cvt(const float* __restrict__ x,
                                                  const float* __restrict__ gw,
                                                  unsigned short* __restrict__ xbf,
                                                  int* __restrict__ ti,
                                                  float* __restrict__ tw) {
  int t = blockIdx.x * 4 + (threadIdx.x >> 6);
  int lane = threadIdx.x & 63;
  const float4* xr = (const float4*)(x + (size_t)t * DIMX);
  ushort4* xo = (ushort4*)(xbf + (size_t)t * DIMX);
  float p[NE];
#pragma unroll
  for (int e = 0; e < NE; e++) p[e] = 0.f;
#pragma unroll
  for (int j = 0; j < 4; j++) {
    int idx4 = j * 64 + lane;
    float4 v = xr[idx4];
    ushort4 o; o.x = f2bf(v.x); o.y = f2bf(v.y); o.z = f2bf(v.z); o.w = f2bf(v.w);
    xo[idx4] = o;
    const float4* gp = (const float4*)(gw + (size_t)(idx4 * 4) * NE);
    float4 gA = gp[0], gB = gp[1], gC = gp[2], gD = gp[3];
    float4 gE = gp[4], gF = gp[5], gG = gp[6], gH = gp[7];
    p[0] += v.x * gA.x + v.y * gC.x + v.z * gE.x + v.w * gG.x;
    p[1] += v.x * gA.y + v.y * gC.y + v.z * gE.y + v.w * gG.y;
    p[2] += v.x * gA.z + v.y * gC.z + v.z * gE.z + v.w * gG.z;
    p[3] += v.x * gA.w + v.y * gC.w + v.z * gE.w + v.w * gG.w;
    p[4] += v.x * gB.x + v.y * gD.x + v.z * gF.x + v.w * gH.x;
    p[5] += v.x * gB.y + v.y * gD.y + v.z * gF.y + v.w * gH.y;
    p[6] += v.x * gB.z + v.y * gD.z + v.z * gF.z + v.w * gH.z;
    p[7] += v.x * gB.w + v.y * gD.w + v.z * gF.w + v.w * gH.w;
  }
#pragma unroll
  for (int e = 0; e < NE; e++)
#pragma unroll
    for (int off = 32; off > 0; off >>= 1) p[e] += __shfl_xor(p[e], off);
  if (lane == 0) {
    int ia = 0; float va = p[0];
#pragma unroll
    for (int e = 1; e < NE; e++) if (p[e] > va) { va = p[e]; ia = e; }
    int ib = -1; float vb = -3.0e38f;
#pragma unroll
    for (int e = 0; e < NE; e++) { if (e == ia) continue; if (p[e] > vb) { vb = p[e]; ib = e; } }
    float w0 = 1.f / (1.f + expf(vb - va));
    ti[t * 2] = ia;     tw[t * 2] = w0;
    ti[t * 2 + 1] = ib; tw[t * 2 + 1] = 1.f - w0;
  }
}

// single block; ti AND tw staged in LDS -> zero global loads in the compaction loop
__global__ __launch_bounds__(512) void k_build(const int* __restrict__ ti,
                                               const float* __restrict__ tw,
                                               int* __restrict__ cnt,
                                               int* __restrict__ poffs,
                                               int* __restrict__ s_e, int* __restrict__ s_r0,
                                               int* __restrict__ ptok, int* __restrict__ ptk,
                                               float* __restrict__ pw) {
  __shared__ int sti[NPAIR];         // 32 KB
  __shared__ float stw[NPAIR];       // 32 KB
  __shared__ int scnt[NE];
  for (int i = threadIdx.x; i < NPAIR; i += 512) { sti[i] = ti[i]; stw[i] = tw[i]; }
  __syncthreads();
  int wid = threadIdx.x >> 6;
  int lane = threadIdx.x & 63;
  int c = 0;
  for (int p = lane; p < NPAIR; p += 64) c += (sti[p] == wid) ? 1 : 0;
#pragma unroll
  for (int off = 32; off > 0; off >>= 1) c += __shfl_xor(c, off);
  if (lane == 0) scnt[wid] = c;
  __syncthreads();
  if (threadIdx.x == 0) {
    int s = 0, pacc = 0;
    for (int e = 0; e < NE; e++) {
      cnt[e] = scnt[e];
      poffs[e] = pacc;
      int ns = (scnt[e] + 127) >> 7;
      for (int k = 0; k < ns; k++) { s_e[s] = e; s_r0[s] = k * 128; s++; }
      pacc += ns * 128;
    }
    poffs[NE] = pacc;
    for (; s < MAXSTRIP; s++) { s_e[s] = -1; s_r0[s] = 0; }
  }
  int base = 0;
  for (int p0 = 0; p0 < NPAIR; p0 += 64) {
    int p = p0 + lane;
    bool m = (sti[p] == wid);
    unsigned long long mask = __ballot(m);
    if (m) {
      int pos = base + __popcll(mask & ((1ull << lane) - 1ull));
      ptok[wid * NT + pos] = p >> 1;
      ptk[wid * NT + pos] = p;
      pw[wid * NT + pos] = stw[p];
    }
    base += __popcll(mask);
  }
}

// 64x64 transpose+convert: out[c][r] = bf16(in[r][c]), per expert slice
__global__ __launch_bounds__(256) void k_transpose_cvt(const float* __restrict__ in,
                                                       unsigned short* __restrict__ out,
                                                       int R, int C) {
  __shared__ float tile[64][73];
  int e = blockIdx.z;
  const float* ip = in + (size_t)e * R * C;
  unsigned short* op = out + (size_t)e * R * C;
  int c0 = blockIdx.x * 64, r0 = blockIdx.y * 64;
  int tx = threadIdx.x & 15, ty = threadIdx.x >> 4;
#pragma unroll
  for (int i = 0; i < 4; i++) {
    int row = ty + i * 16;
    float4 v = *(const float4*)(ip + (size_t)(r0 + row) * C + c0 + tx * 4);
    tile[row][tx * 4] = v.x; tile[row][tx * 4 + 1] = v.y;
    tile[row][tx * 4 + 2] = v.z; tile[row][tx * 4 + 3] = v.w;
  }
  __syncthreads();
  int rx = threadIdx.x & 15, cy = threadIdx.x >> 4;
  int r_off = rx * 4;
#pragma unroll
  for (int i = 0; i < 4; i++) {
    int cc = cy + i * 16;
    ushort4 h;
    h.x = f2bf(tile[r_off][cc]);     h.y = f2bf(tile[r_off + 1][cc]);
    h.z = f2bf(tile[r_off + 2][cc]); h.w = f2bf(tile[r_off + 3][cc]);
    *(ushort4*)(op + (size_t)(c0 + cc) * R + r0 + r_off) = h;
  }
}

#define BM 128
#define BN 128
#define BK 64
// BK=64: 128-byte LDS rows (8x 16B chunks) + XOR chunk swizzle (csrc = c ^ (row&7))
// -> fragment ds_read_b128 phases hit all 8 bank-groups (2-way only, free per m136),
//    and half the barriers of BK=32 (32 MFMA per barrier pair).

// GEMM1: hpre[poffs[e]+g][:] = gathered_x[tok] @ w1T[e]^T + b1[e]
__global__ __launch_bounds__(256) void k_gemm1(
    const unsigned short* __restrict__ xbf,
    const unsigned short* __restrict__ w1t,
    const float* __restrict__ bias1,
    const int* __restrict__ cnt, const int* __restrict__ s_e,
    const int* __restrict__ s_r0, const int* __restrict__ poffs,
    const int* __restrict__ ptok,
    unsigned short* __restrict__ hpre)
{
  int s = blockIdx.y;
  int e = s_e[s];
  if (e < 0) return;
  int r0e = s_r0[s];
  int n_e = cnt[e];
  int pbase = poffs[e];
  int col0 = blockIdx.x * BN;

  __shared__ __align__(16) unsigned short As[BM][BK];
  __shared__ __align__(16) unsigned short Bs[BN][BK];

  int tid = threadIdx.x;
  int lane = tid & 63, wid = tid >> 6;
  int wr = wid >> 1, wc = wid & 1;
  int quad = lane >> 4, m16 = lane & 15;

  // staging: each instr covers 8 rows x 128B. lane -> row r8=lane>>3, chunk c8=lane&7.
  // source chunk swizzled: csrc = c8 ^ r8 (row&7 == r8 for all groups).
  int r8 = lane >> 3, c8 = lane & 7;
  int csrc = (c8 ^ r8) * 8;   // ushort offset
  const unsigned short* aP[4];
  const unsigned short* bP[4];
  const unsigned short* bbase = w1t + (size_t)e * HID * DIMX;
#pragma unroll
  for (int t = 0; t < 4; t++) {
    int gr = r0e + wid * 32 + t * 8 + r8; if (gr >= n_e) gr = n_e - 1;
    int tok = ptok[e * NT + gr];
    aP[t] = xbf + (size_t)tok * DIMX + csrc;
    int gc = col0 + wid * 32 + t * 8 + r8;
    bP[t] = bbase + (size_t)gc * DIMX + csrc;
  }

  f32x4 acc[4][4];
#pragma unroll
  for (int i = 0; i < 4; i++)
#pragma unroll
    for (int j = 0; j < 4; j++) acc[i][j] = (f32x4)(0.f);

  for (int k0 = 0; k0 < DIMX; k0 += BK) {
    __syncthreads();
#pragma unroll
    for (int t = 0; t < 4; t++) gload_lds16(aP[t] + k0, &As[wid * 32 + t * 8][0]);
#pragma unroll
    for (int t = 0; t < 4; t++) gload_lds16(bP[t] + k0, &Bs[wid * 32 + t * 8][0]);
    __syncthreads();
#pragma unroll
    for (int ks = 0; ks < 2; ks++) {
      int ca = (((quad + 4 * ks) ^ (m16 & 7))) * 8;
      bf16x8 af[4], bfr[4];
#pragma unroll
      for (int i = 0; i < 4; i++) af[i]  = *(const bf16x8*)&As[wr * 64 + i * 16 + m16][ca];
#pragma unroll
      for (int j = 0; j < 4; j++) bfr[j] = *(const bf16x8*)&Bs[wc * 64 + j * 16 + m16][ca];
#pragma unroll
      for (int i = 0; i < 4; i++)
#pragma unroll
        for (int j = 0; j < 4; j++)
          acc[i][j] = __builtin_amdgcn_mfma_f32_16x16x32_bf16(af[i], bfr[j], acc[i][j], 0, 0, 0);
    }
  }

  float bj[4];
#pragma unroll
  for (int j = 0; j < 4; j++) bj[j] = bias1[e * HID + col0 + wc * 64 + j * 16 + m16];
#pragma unroll
  for (int i = 0; i < 4; i++) {
#pragma unroll
    for (int r = 0; r < 4; r++) {
      int g = r0e + wr * 64 + i * 16 + quad * 4 + r;
      if (g < n_e) {
        size_t rowbase = (size_t)(pbase + g) * HID;
#pragma unroll
        for (int j = 0; j < 4; j++) {
          int colg = col0 + wc * 64 + j * 16 + m16;
          hpre[rowbase + colg] = f2bf(acc[i][j][r] + bj[j]);
        }
      }
    }
  }
}

// in-place row LayerNorm + exact GELU over HID (padded rows)
__global__ __launch_bounds__(256) void k_ln_gelu(unsigned short* __restrict__ h,
                                                 const float* __restrict__ g1,
                                                 const float* __restrict__ bb1,
                                                 const int* __restrict__ s_e) {
  __shared__ float sbuf[4];
  int row = blockIdx.x;
  int e = s_e[row >> 7];
  if (e < 0) return;
  int tid = threadIdx.x;
  unsigned short* p = h + (size_t)row * HID;
  ushort4 u0 = ((const ushort4*)p)[tid * 2];
  ushort4 u1 = ((const ushort4*)p)[tid * 2 + 1];
  float v[8];
  v[0] = bf2f(u0.x); v[1] = bf2f(u0.y); v[2] = bf2f(u0.z); v[3] = bf2f(u0.w);
  v[4] = bf2f(u1.x); v[5] = bf2f(u1.y); v[6] = bf2f(u1.z); v[7] = bf2f(u1.w);
  float s = 0.f;
#pragma unroll
  for (int i = 0; i < 8; i++) s += v[i];
#pragma unroll
  for (int off = 32; off > 0; off >>= 1) s += __shfl_xor(s, off);
  if ((tid & 63) == 0) sbuf[tid >> 6] = s;
  __syncthreads();
  float mean = (sbuf[0] + sbuf[1] + sbuf[2] + sbuf[3]) * (1.f / HID);
  float sq = 0.f;
#pragma unroll
  for (int i = 0; i < 8; i++) { float d = v[i] - mean; sq += d * d; }
#pragma unroll
  for (int off = 32; off > 0; off >>= 1) sq += __shfl_xor(sq, off);
  __syncthreads();
  if ((tid & 63) == 0) sbuf[tid >> 6] = sq;
  __syncthreads();
  float var = (sbuf[0] + sbuf[1] + sbuf[2] + sbuf[3]) * (1.f / HID);
  float rstd = rsqrtf(var + 1e-5f);
  const float4* gg = (const float4*)(g1 + (size_t)e * HID);
  const float4* gb = (const float4*)(bb1 + (size_t)e * HID);
  float4 ga = gg[tid * 2], gbv = gg[tid * 2 + 1];
  float4 ba = gb[tid * 2], bbv = gb[tid * 2 + 1];
  float gn[8] = {ga.x, ga.y, ga.z, ga.w, gbv.x, gbv.y, gbv.z, gbv.w};
  float bn[8] = {ba.x, ba.y, ba.z, ba.w, bbv.x, bbv.y, bbv.z, bbv.w};
  unsigned short o[8];
#pragma unroll
  for (int i = 0; i < 8; i++) {
    float xn = (v[i] - mean) * rstd * gn[i] + bn[i];
    float ge = 0.5f * xn * (1.f + erff(xn * 0.7071067811865476f));
    o[i] = f2bf(ge);
  }
  ushort4 s0 = {o[0], o[1], o[2], o[3]};
  ushort4 s1 = {o[4], o[5], o[6], o[7]};
  ((ushort4*)p)[tid * 2] = s0;
  ((ushort4*)p)[tid * 2 + 1] = s1;
}

// GEMM2: ybuf[ptk] = (h_row @ w2T[e]^T + b2[e]) * gate_weight
__global__ __launch_bounds__(256) void k_gemm2(
    const unsigned short* __restrict__ hb,
    const unsigned short* __restrict__ w2t,
    const float* __restrict__ bias2,
    const int* __restrict__ cnt, const int* __restrict__ s_e,
    const int* __restrict__ s_r0, const int* __restrict__ poffs,
    const int* __restrict__ ptk, const float* __restrict__ pw,
    float* __restrict__ ybuf)
{
  int s = blockIdx.y;
  int e = s_e[s];
  if (e < 0) return;
  int r0e = s_r0[s];
  int n_e = cnt[e];
  int pbase = poffs[e];
  int col0 = blockIdx.x * BN;

  __shared__ __align__(16) unsigned short As[BM][BK];
  __shared__ __align__(16) unsigned short Bs[BN][BK];

  int tid = threadIdx.x;
  int lane = tid & 63, wid = tid >> 6;
  int wr = wid >> 1, wc = wid & 1;
  int quad = lane >> 4, m16 = lane & 15;

  int r8 = lane >> 3, c8 = lane & 7;
  int csrc = (c8 ^ r8) * 8;
  const unsigned short* aP[4];
  const unsigned short* bP[4];
  const unsigned short* bbase = w2t + (size_t)e * DIMX * HID;
#pragma unroll
  for (int t = 0; t < 4; t++) {
    int gr = r0e + wid * 32 + t * 8 + r8; if (gr >= n_e) gr = n_e - 1;
    aP[t] = hb + (size_t)(pbase + gr) * HID + csrc;
    int gc = col0 + wid * 32 + t * 8 + r8;
    bP[t] = bbase + (size_t)gc * HID + csrc;
  }

  f32x4 acc[4][4];
#pragma unroll
  for (int i = 0; i < 4; i++)
#pragma unroll
    for (int j = 0; j < 4; j++) acc[i][j] = (f32x4)(0.f);

  for (int k0 = 0; k0 < HID; k0 += BK) {
    __syncthreads();
#pragma unroll
    for (int t = 0; t < 4; t++) gload_lds16(aP[t] + k0, &As[wid * 32 + t * 8][0]);
#pragma unroll
    for (int t = 0; t < 4; t++) gload_lds16(bP[t] + k0, &Bs[wid * 32 + t * 8][0]);
    __syncthreads();
#pragma unroll
    for (int ks = 0; ks < 2; ks++) {
      int ca = (((quad + 4 * ks) ^ (m16 & 7))) * 8;
      bf16x8 af[4], bfr[4];
#pragma unroll
      for (int i = 0; i < 4; i++) af[i]  = *(const bf16x8*)&As[wr * 64 + i * 16 + m16][ca];
#pragma unroll
      for (int j = 0; j < 4; j++) bfr[j] = *(const bf16x8*)&Bs[wc * 64 + j * 16 + m16][ca];
#pragma unroll
      for (int i = 0; i < 4; i++)
#pragma unroll
        for (int j = 0; j < 4; j++)
          acc[i][j] = __builtin_amdgcn_mfma_f32_16x16x32_bf16(af[i], bfr[j], acc[i][j], 0, 0, 0);
    }
  }

  float bj[4];
#pragma unroll
  for (int j = 0; j < 4; j++) bj[j] = bias2[e * DIMX + col0 + wc * 64 + j * 16 + m16];
#pragma unroll
  for (int i = 0; i < 4; i++) {
#pragma unroll
    for (int r = 0; r < 4; r++) {
      int g = r0e + wr * 64 + i * 16 + quad * 4 + r;
      if (g < n_e) {
        int pi = e * NT + g;
        float w = pw[pi];
        size_t obase = (size_t)ptk[pi] * DIMX;
#pragma unroll
        for (int j = 0; j < 4; j++) {
          int colg = col0 + wc * 64 + j * 16 + m16;
          ybuf[obase + colg] = (acc[i][j][r] + bj[j]) * w;
        }
      }
    }
  }
}

// out = LN(y_slot0 + y_slot1 + x)
__global__ __launch_bounds__(256) void k_final(const float* __restrict__ yb,
                                               const float* __restrict__ x,
                                               const float* __restrict__ lg,
                                               const float* __restrict__ lb,
                                               float* __restrict__ out) {
  __shared__ float sbuf[4];
  int t = blockIdx.x, tid = threadIdx.x;
  const float4* y0 = (const float4*)(yb + (size_t)t * 2 * DIMX);
  const float4* y1 = y0 + DIMX / 4;
  const float4* x4 = (const float4*)(x + (size_t)t * DIMX);
  float4 a = y0[tid], b = y1[tid], c = x4[tid];
  float4 v; v.x = a.x + b.x + c.x; v.y = a.y + b.y + c.y;
  v.z = a.z + b.z + c.z; v.w = a.w + b.w + c.w;
  float s = v.x + v.y + v.z + v.w;
#pragma unroll
  for (int off = 32; off > 0; off >>= 1) s += __shfl_xor(s, off);
  if ((tid & 63) == 0) sbuf[tid >> 6] = s;
  __syncthreads();
  float mean = (sbuf[0] + sbuf[1] + sbuf[2] + sbuf[3]) * (1.f / DIMX);
  float dx = v.x - mean, dy = v.y - mean, dz = v.z - mean, dw = v.w - mean;
  float sq = dx * dx + dy * dy + dz * dz + dw * dw;
#pragma unroll
  for (int off = 32; off > 0; off >>= 1) sq += __shfl_xor(sq, off);
  __syncthreads();
  if ((tid & 63) == 0) sbuf[tid >> 6] = sq;
  __syncthreads();
  float var = (sbuf[0] + sbuf[1] + sbuf[2] + sbuf[3]) * (1.f / DIMX);
  float rstd = rsqrtf(var + 1e-5f);
  float4 g = ((const float4*)lg)[tid], bb = ((const float4*)lb)[tid];
  float4 o; o.x = dx * rstd * g.x + bb.x; o.y = dy * rstd * g.y + bb.y;
  o.z = dz * rstd * g.z + bb.z; o.w = dw * rstd * g.w + bb.w;
  ((float4*)(out + (size_t)t * DIMX))[tid] = o;
}

extern "C" void kernel_launch(void* const* d_in, const int* in_sizes, int n_in,
                              void* d_out, int out_size, void* d_ws, size_t ws_size,
                              hipStream_t stream) {
  const float* x     = (const float*)d_in[0];
  const float* gw    = (const float*)d_in[1];
  const float* w1    = (const float*)d_in[2];
  const float* b1    = (const float*)d_in[3];
  const float* ln1g  = (const float*)d_in[4];
  const float* ln1b  = (const float*)d_in[5];
  const float* w2    = (const float*)d_in[6];
  const float* b2    = (const float*)d_in[7];
  const float* lng   = (const float*)d_in[8];
  const float* lnb   = (const float*)d_in[9];
  float* out = (float*)d_out;

  char* ws = (char*)d_ws;
  int* cnt   = (int*)(ws + O_CNT);
  int* ptok  = (int*)(ws + O_TOK);
  int* ptk   = (int*)(ws + O_TK);
  float* pw  = (float*)(ws + O_PW);
  int* ti    = (int*)(ws + O_TI);
  float* tw  = (float*)(ws + O_TW);
  int* poffs = (int*)(ws + O_POFF);
  int* s_e   = (int*)(ws + O_SE);
  int* s_r0  = (int*)(ws + O_SR0);
  unsigned short* xbf  = (unsigned short*)(ws + O_XBF);
  unsigned short* w1t  = (unsigned short*)(ws + O_W1T);
  unsigned short* w2t  = (unsigned short*)(ws + O_W2T);
  unsigned short* hpre = (unsigned short*)(ws + O_H);
  float* ybuf = (float*)(ws + O_Y);

  hipLaunchKernelGGL(k_gate_cvt, dim3(NT / 4), dim3(256), 0, stream, x, gw, xbf, ti, tw);
  hipLaunchKernelGGL(k_build, dim3(1), dim3(512), 0, stream, ti, tw, cnt, poffs, s_e, s_r0,
                     ptok, ptk, pw);
  hipLaunchKernelGGL(k_transpose_cvt, dim3(HID / 64, DIMX / 64, NE), dim3(256), 0, stream,
                     w1, w1t, DIMX, HID);
  hipLaunchKernelGGL(k_transpose_cvt, dim3(DIMX / 64, HID / 64, NE), dim3(256), 0, stream,
                     w2, w2t, HID, DIMX);
  hipLaunchKernelGGL(k_gemm1, dim3(HID / BN, MAXSTRIP), dim3(256), 0, stream,
                     xbf, w1t, b1, cnt, s_e, s_r0, poffs, ptok, hpre);
  hipLaunchKernelGGL(k_ln_gelu, dim3(MAXSTRIP * BM), dim3(256), 0, stream, hpre, ln1g, ln1b, s_e);
  hipLaunchKernelGGL(k_gemm2, dim3(DIMX / BN, MAXSTRIP), dim3(256), 0, stream,
                     hpre, w2t, b2, cnt, s_e, s_r0, poffs, ptk, pw, ybuf);
  hipLaunchKernelGGL(k_final, dim3(NT), dim3(256), 0, stream, ybuf, x, lng, lnb, out);
}

// Round 6
// 377.200 us; speedup vs baseline: 1.2753x; 1.0372x over previous
//
#include <hip/hip_runtime.h>
#include <hip/hip_bf16.h>

#define DIMX 1024
#define HID  2048
#define NE   8
#define NT   4096
#define NPAIR 8192
#define MAXSTRIP 72

typedef __attribute__((ext_vector_type(8))) __bf16 bf16x8;
typedef __attribute__((ext_vector_type(4))) float f32x4;

__device__ inline unsigned short f2bf(float f) {
  union { float f; unsigned u; } v; v.f = f;
  unsigned r = v.u + 0x7FFFu + ((v.u >> 16) & 1u);
  return (unsigned short)(r >> 16);
}
__device__ inline float bf2f(unsigned short h) {
  union { unsigned u; float f; } v; v.u = ((unsigned)h) << 16;
  return v.f;
}

__device__ __forceinline__ void gload_lds16(const unsigned short* g, unsigned short* l) {
  __builtin_amdgcn_global_load_lds(
      (const __attribute__((address_space(1))) unsigned int*)g,
      (__attribute__((address_space(3))) unsigned int*)l, 16, 0, 0);
}

// ---------------- workspace layout (bytes) ----------------
#define O_CNT   0u
#define O_TOK   1024u
#define O_TK    132096u
#define O_PW    263168u
#define O_TI    394240u
#define O_TW    427008u
#define O_POFF  459776u
#define O_SE    459904u
#define O_SR0   460416u
#define O_XBF   524288u        // 4096*1024 bf16
#define O_W1T   16777216u      // 8*2048*1024 bf16
#define O_W2T   50331648u      // 8*1024*2048 bf16
#define O_H     83886080u      // 9216*2048 bf16 (padded rows)
#define O_Y     121634816u     // 8192*1024 f32

// fused: bf16-convert x row + gate logits + top-2 (one wave per token)
__global__ __launch_bounds__(256) void k_gate_cvt(const float* __restrict__ x,
                                                  const float* __restrict__ gw,
                                                  unsigned short* __restrict__ xbf,
                                                  int* __restrict__ ti,
                                                  float* __restrict__ tw) {
  int t = blockIdx.x * 4 + (threadIdx.x >> 6);
  int lane = threadIdx.x & 63;
  const float4* xr = (const float4*)(x + (size_t)t * DIMX);
  ushort4* xo = (ushort4*)(xbf + (size_t)t * DIMX);
  float p[NE];
#pragma unroll
  for (int e = 0; e < NE; e++) p[e] = 0.f;
#pragma unroll
  for (int j = 0; j < 4; j++) {
    int idx4 = j * 64 + lane;
    float4 v = xr[idx4];
    ushort4 o; o.x = f2bf(v.x); o.y = f2bf(v.y); o.z = f2bf(v.z); o.w = f2bf(v.w);
    xo[idx4] = o;
    const float4* gp = (const float4*)(gw + (size_t)(idx4 * 4) * NE);
    float4 gA = gp[0], gB = gp[1], gC = gp[2], gD = gp[3];
    float4 gE = gp[4], gF = gp[5], gG = gp[6], gH = gp[7];
    p[0] += v.x * gA.x + v.y * gC.x + v.z * gE.x + v.w * gG.x;
    p[1] += v.x * gA.y + v.y * gC.y + v.z * gE.y + v.w * gG.y;
    p[2] += v.x * gA.z + v.y * gC.z + v.z * gE.z + v.w * gG.z;
    p[3] += v.x * gA.w + v.y * gC.w + v.z * gE.w + v.w * gG.w;
    p[4] += v.x * gB.x + v.y * gD.x + v.z * gF.x + v.w * gH.x;
    p[5] += v.x * gB.y + v.y * gD.y + v.z * gF.y + v.w * gH.y;
    p[6] += v.x * gB.z + v.y * gD.z + v.z * gF.z + v.w * gH.z;
    p[7] += v.x * gB.w + v.y * gD.w + v.z * gF.w + v.w * gH.w;
  }
#pragma unroll
  for (int e = 0; e < NE; e++)
#pragma unroll
    for (int off = 32; off > 0; off >>= 1) p[e] += __shfl_xor(p[e], off);
  if (lane == 0) {
    int ia = 0; float va = p[0];
#pragma unroll
    for (int e = 1; e < NE; e++) if (p[e] > va) { va = p[e]; ia = e; }
    int ib = -1; float vb = -3.0e38f;
#pragma unroll
    for (int e = 0; e < NE; e++) { if (e == ia) continue; if (p[e] > vb) { vb = p[e]; ib = e; } }
    float w0 = 1.f / (1.f + expf(vb - va));
    ti[t * 2] = ia;     tw[t * 2] = w0;
    ti[t * 2 + 1] = ib; tw[t * 2 + 1] = 1.f - w0;
  }
}

// single block; ti AND tw staged in LDS -> zero global loads in the compaction loop
__global__ __launch_bounds__(512) void k_build(const int* __restrict__ ti,
                                               const float* __restrict__ tw,
                                               int* __restrict__ cnt,
                                               int* __restrict__ poffs,
                                               int* __restrict__ s_e, int* __restrict__ s_r0,
                                               int* __restrict__ ptok, int* __restrict__ ptk,
                                               float* __restrict__ pw) {
  __shared__ int sti[NPAIR];
  __shared__ float stw[NPAIR];
  __shared__ int scnt[NE];
  for (int i = threadIdx.x; i < NPAIR; i += 512) { sti[i] = ti[i]; stw[i] = tw[i]; }
  __syncthreads();
  int wid = threadIdx.x >> 6;
  int lane = threadIdx.x & 63;
  int c = 0;
  for (int p = lane; p < NPAIR; p += 64) c += (sti[p] == wid) ? 1 : 0;
#pragma unroll
  for (int off = 32; off > 0; off >>= 1) c += __shfl_xor(c, off);
  if (lane == 0) scnt[wid] = c;
  __syncthreads();
  if (threadIdx.x == 0) {
    int s = 0, pacc = 0;
    for (int e = 0; e < NE; e++) {
      cnt[e] = scnt[e];
      poffs[e] = pacc;
      int ns = (scnt[e] + 127) >> 7;
      for (int k = 0; k < ns; k++) { s_e[s] = e; s_r0[s] = k * 128; s++; }
      pacc += ns * 128;
    }
    poffs[NE] = pacc;
    for (; s < MAXSTRIP; s++) { s_e[s] = -1; s_r0[s] = 0; }
  }
  int base = 0;
  for (int p0 = 0; p0 < NPAIR; p0 += 64) {
    int p = p0 + lane;
    bool m = (sti[p] == wid);
    unsigned long long mask = __ballot(m);
    if (m) {
      int pos = base + __popcll(mask & ((1ull << lane) - 1ull));
      ptok[wid * NT + pos] = p >> 1;
      ptk[wid * NT + pos] = p;
      pw[wid * NT + pos] = stw[p];
    }
    base += __popcll(mask);
  }
}

// 64x64 transpose+convert: out[c][r] = bf16(in[r][c]), per expert slice
__global__ __launch_bounds__(256) void k_transpose_cvt(const float* __restrict__ in,
                                                       unsigned short* __restrict__ out,
                                                       int R, int C) {
  __shared__ float tile[64][73];
  int e = blockIdx.z;
  const float* ip = in + (size_t)e * R * C;
  unsigned short* op = out + (size_t)e * R * C;
  int c0 = blockIdx.x * 64, r0 = blockIdx.y * 64;
  int tx = threadIdx.x & 15, ty = threadIdx.x >> 4;
#pragma unroll
  for (int i = 0; i < 4; i++) {
    int row = ty + i * 16;
    float4 v = *(const float4*)(ip + (size_t)(r0 + row) * C + c0 + tx * 4);
    tile[row][tx * 4] = v.x; tile[row][tx * 4 + 1] = v.y;
    tile[row][tx * 4 + 2] = v.z; tile[row][tx * 4 + 3] = v.w;
  }
  __syncthreads();
  int rx = threadIdx.x & 15, cy = threadIdx.x >> 4;
  int r_off = rx * 4;
#pragma unroll
  for (int i = 0; i < 4; i++) {
    int cc = cy + i * 16;
    ushort4 h;
    h.x = f2bf(tile[r_off][cc]);     h.y = f2bf(tile[r_off + 1][cc]);
    h.z = f2bf(tile[r_off + 2][cc]); h.w = f2bf(tile[r_off + 3][cc]);
    *(ushort4*)(op + (size_t)(c0 + cc) * R + r0 + r_off) = h;
  }
}

#define BM 128
#define BN 128
#define BK 32
// BK=32 (16 KB LDS, R4 occupancy) + conflict-free swizzle on 64B rows:
// store chunk = c ^ ((row>>1)&3), read chunk = quad ^ ((m16>>1)&3).
// A read phase's 16 lanes cover all 8 16B positions of the 128B bank space (2-way, free).

// GEMM1: hpre[poffs[e]+g][:] = gathered_x[tok] @ w1T[e]^T + b1[e]
__global__ __launch_bounds__(256) void k_gemm1(
    const unsigned short* __restrict__ xbf,
    const unsigned short* __restrict__ w1t,
    const float* __restrict__ bias1,
    const int* __restrict__ cnt, const int* __restrict__ s_e,
    const int* __restrict__ s_r0, const int* __restrict__ poffs,
    const int* __restrict__ ptok,
    unsigned short* __restrict__ hpre)
{
  int s = blockIdx.y;
  int e = s_e[s];
  if (e < 0) return;
  int r0e = s_r0[s];
  int n_e = cnt[e];
  int pbase = poffs[e];
  int col0 = blockIdx.x * BN;

  __shared__ __align__(16) unsigned short As[BM][BK];
  __shared__ __align__(16) unsigned short Bs[BN][BK];

  int tid = threadIdx.x;
  int lane = tid & 63, wid = tid >> 6;
  int wr = wid >> 1, wc = wid & 1;
  int quad = lane >> 4, m16 = lane & 15;

  // staging: 2 instrs/operand/wave, each 16 rows x 64B. lane -> row lane>>2,
  // physical chunk lane&3; source fetches logical chunk (lane&3)^((lane>>3)&3).
  int rr = lane >> 2;
  int csrc = ((lane & 3) ^ ((lane >> 3) & 3)) * 8;
  int ga0 = r0e + wid * 32 + rr;      if (ga0 >= n_e) ga0 = n_e - 1;
  int ga1 = r0e + wid * 32 + 16 + rr; if (ga1 >= n_e) ga1 = n_e - 1;
  int t0 = ptok[e * NT + ga0];
  int t1 = ptok[e * NT + ga1];
  const unsigned short* a0p = xbf + (size_t)t0 * DIMX + csrc;
  const unsigned short* a1p = xbf + (size_t)t1 * DIMX + csrc;
  const unsigned short* bbase = w1t + (size_t)e * HID * DIMX;
  const unsigned short* b0p = bbase + (size_t)(col0 + wid * 32 + rr) * DIMX + csrc;
  const unsigned short* b1p = bbase + (size_t)(col0 + wid * 32 + 16 + rr) * DIMX + csrc;
  unsigned short* lA0 = &As[wid * 32][0];
  unsigned short* lA1 = &As[wid * 32 + 16][0];
  unsigned short* lB0 = &Bs[wid * 32][0];
  unsigned short* lB1 = &Bs[wid * 32 + 16][0];

  int ca = (quad ^ ((m16 >> 1) & 3)) * 8;

  f32x4 acc[4][4];
#pragma unroll
  for (int i = 0; i < 4; i++)
#pragma unroll
    for (int j = 0; j < 4; j++) acc[i][j] = (f32x4)(0.f);

  for (int k0 = 0; k0 < DIMX; k0 += BK) {
    __syncthreads();
    gload_lds16(a0p + k0, lA0);
    gload_lds16(a1p + k0, lA1);
    gload_lds16(b0p + k0, lB0);
    gload_lds16(b1p + k0, lB1);
    __syncthreads();
    bf16x8 af[4], bfr[4];
#pragma unroll
    for (int i = 0; i < 4; i++) af[i]  = *(const bf16x8*)&As[wr * 64 + i * 16 + m16][ca];
#pragma unroll
    for (int j = 0; j < 4; j++) bfr[j] = *(const bf16x8*)&Bs[wc * 64 + j * 16 + m16][ca];
#pragma unroll
    for (int i = 0; i < 4; i++)
#pragma unroll
      for (int j = 0; j < 4; j++)
        acc[i][j] = __builtin_amdgcn_mfma_f32_16x16x32_bf16(af[i], bfr[j], acc[i][j], 0, 0, 0);
  }

  float bj[4];
#pragma unroll
  for (int j = 0; j < 4; j++) bj[j] = bias1[e * HID + col0 + wc * 64 + j * 16 + m16];
#pragma unroll
  for (int i = 0; i < 4; i++) {
#pragma unroll
    for (int r = 0; r < 4; r++) {
      int g = r0e + wr * 64 + i * 16 + quad * 4 + r;
      if (g < n_e) {
        size_t rowbase = (size_t)(pbase + g) * HID;
#pragma unroll
        for (int j = 0; j < 4; j++) {
          int colg = col0 + wc * 64 + j * 16 + m16;
          hpre[rowbase + colg] = f2bf(acc[i][j][r] + bj[j]);
        }
      }
    }
  }
}

// one wave per row: LayerNorm + exact GELU over HID, no barriers
__global__ __launch_bounds__(256) void k_ln_gelu(unsigned short* __restrict__ h,
                                                 const float* __restrict__ g1,
                                                 const float* __restrict__ bb1,
                                                 const int* __restrict__ s_e) {
  int row = blockIdx.x * 4 + (threadIdx.x >> 6);
  int e = s_e[row >> 7];
  if (e < 0) return;
  int lane = threadIdx.x & 63;
  unsigned short* p = h + (size_t)row * HID;
  int4* p4 = (int4*)p;                 // 8 bf16 per int4; 256 per row
  int4 raw[4];
#pragma unroll
  for (int sg = 0; sg < 4; sg++) raw[sg] = p4[sg * 64 + lane];
  float v[32];
#pragma unroll
  for (int sg = 0; sg < 4; sg++) {
    const unsigned short* u = (const unsigned short*)&raw[sg];
#pragma unroll
    for (int k = 0; k < 8; k++) v[sg * 8 + k] = bf2f(u[k]);
  }
  float s = 0.f;
#pragma unroll
  for (int i = 0; i < 32; i++) s += v[i];
#pragma unroll
  for (int off = 32; off > 0; off >>= 1) s += __shfl_xor(s, off);
  float mean = s * (1.f / HID);
  float sq = 0.f;
#pragma unroll
  for (int i = 0; i < 32; i++) { float d = v[i] - mean; sq += d * d; }
#pragma unroll
  for (int off = 32; off > 0; off >>= 1) sq += __shfl_xor(sq, off);
  float rstd = rsqrtf(sq * (1.f / HID) + 1e-5f);
  const float4* gg = (const float4*)(g1 + (size_t)e * HID);
  const float4* gb = (const float4*)(bb1 + (size_t)e * HID);
#pragma unroll
  for (int sg = 0; sg < 4; sg++) {
    float4 ga = gg[sg * 128 + lane * 2], gc = gg[sg * 128 + lane * 2 + 1];
    float4 ba = gb[sg * 128 + lane * 2], bc = gb[sg * 128 + lane * 2 + 1];
    float gn[8] = {ga.x, ga.y, ga.z, ga.w, gc.x, gc.y, gc.z, gc.w};
    float bn[8] = {ba.x, ba.y, ba.z, ba.w, bc.x, bc.y, bc.z, bc.w};
    unsigned short o[8];
#pragma unroll
    for (int k = 0; k < 8; k++) {
      float xn = (v[sg * 8 + k] - mean) * rstd * gn[k] + bn[k];
      float ge = 0.5f * xn * (1.f + erff(xn * 0.7071067811865476f));
      o[k] = f2bf(ge);
    }
    p4[sg * 64 + lane] = *(const int4*)o;
  }
}

// GEMM2: ybuf[ptk] = (h_row @ w2T[e]^T + b2[e]) * gate_weight
__global__ __launch_bounds__(256) void k_gemm2(
    const unsigned short* __restrict__ hb,
    const unsigned short* __restrict__ w2t,
    const float* __restrict__ bias2,
    const int* __restrict__ cnt, const int* __restrict__ s_e,
    const int* __restrict__ s_r0, const int* __restrict__ poffs,
    const int* __restrict__ ptk, const float* __restrict__ pw,
    float* __restrict__ ybuf)
{
  int s = blockIdx.y;
  int e = s_e[s];
  if (e < 0) return;
  int r0e = s_r0[s];
  int n_e = cnt[e];
  int pbase = poffs[e];
  int col0 = blockIdx.x * BN;

  __shared__ __align__(16) unsigned short As[BM][BK];
  __shared__ __align__(16) unsigned short Bs[BN][BK];

  int tid = threadIdx.x;
  int lane = tid & 63, wid = tid >> 6;
  int wr = wid >> 1, wc = wid & 1;
  int quad = lane >> 4, m16 = lane & 15;

  int rr = lane >> 2;
  int csrc = ((lane & 3) ^ ((lane >> 3) & 3)) * 8;
  int ga0 = r0e + wid * 32 + rr;      if (ga0 >= n_e) ga0 = n_e - 1;
  int ga1 = r0e + wid * 32 + 16 + rr; if (ga1 >= n_e) ga1 = n_e - 1;
  const unsigned short* a0p = hb + (size_t)(pbase + ga0) * HID + csrc;
  const unsigned short* a1p = hb + (size_t)(pbase + ga1) * HID + csrc;
  const unsigned short* bbase = w2t + (size_t)e * DIMX * HID;
  const unsigned short* b0p = bbase + (size_t)(col0 + wid * 32 + rr) * HID + csrc;
  const unsigned short* b1p = bbase + (size_t)(col0 + wid * 32 + 16 + rr) * HID + csrc;
  unsigned short* lA0 = &As[wid * 32][0];
  unsigned short* lA1 = &As[wid * 32 + 16][0];
  unsigned short* lB0 = &Bs[wid * 32][0];
  unsigned short* lB1 = &Bs[wid * 32 + 16][0];

  int ca = (quad ^ ((m16 >> 1) & 3)) * 8;

  f32x4 acc[4][4];
#pragma unroll
  for (int i = 0; i < 4; i++)
#pragma unroll
    for (int j = 0; j < 4; j++) acc[i][j] = (f32x4)(0.f);

  for (int k0 = 0; k0 < HID; k0 += BK) {
    __syncthreads();
    gload_lds16(a0p + k0, lA0);
    gload_lds16(a1p + k0, lA1);
    gload_lds16(b0p + k0, lB0);
    gload_lds16(b1p + k0, lB1);
    __syncthreads();
    bf16x8 af[4], bfr[4];
#pragma unroll
    for (int i = 0; i < 4; i++) af[i]  = *(const bf16x8*)&As[wr * 64 + i * 16 + m16][ca];
#pragma unroll
    for (int j = 0; j < 4; j++) bfr[j] = *(const bf16x8*)&Bs[wc * 64 + j * 16 + m16][ca];
#pragma unroll
    for (int i = 0; i < 4; i++)
#pragma unroll
      for (int j = 0; j < 4; j++)
        acc[i][j] = __builtin_amdgcn_mfma_f32_16x16x32_bf16(af[i], bfr[j], acc[i][j], 0, 0, 0);
  }

  float bj[4];
#pragma unroll
  for (int j = 0; j < 4; j++) bj[j] = bias2[e * DIMX + col0 + wc * 64 + j * 16 + m16];
#pragma unroll
  for (int i = 0; i < 4; i++) {
#pragma unroll
    for (int r = 0; r < 4; r++) {
      int g = r0e + wr * 64 + i * 16 + quad * 4 + r;
      if (g < n_e) {
        int pi = e * NT + g;
        float w = pw[pi];
        size_t obase = (size_t)ptk[pi] * DIMX;
#pragma unroll
        for (int j = 0; j < 4; j++) {
          int colg = col0 + wc * 64 + j * 16 + m16;
          ybuf[obase + colg] = (acc[i][j][r] + bj[j]) * w;
        }
      }
    }
  }
}

// one wave per token: out = LN(y_slot0 + y_slot1 + x), no barriers
__global__ __launch_bounds__(256) void k_final(const float* __restrict__ yb,
                                               const float* __restrict__ x,
                                               const float* __restrict__ lg,
                                               const float* __restrict__ lb,
                                               float* __restrict__ out) {
  int t = blockIdx.x * 4 + (threadIdx.x >> 6);
  int lane = threadIdx.x & 63;
  const float4* y0 = (const float4*)(yb + (size_t)t * 2 * DIMX);
  const float4* y1 = y0 + DIMX / 4;
  const float4* x4 = (const float4*)(x + (size_t)t * DIMX);
  float4 v[4];
  float s = 0.f;
#pragma unroll
  for (int sg = 0; sg < 4; sg++) {
    int idx = sg * 64 + lane;
    float4 a = y0[idx], b = y1[idx], c = x4[idx];
    v[sg].x = a.x + b.x + c.x; v[sg].y = a.y + b.y + c.y;
    v[sg].z = a.z + b.z + c.z; v[sg].w = a.w + b.w + c.w;
    s += v[sg].x + v[sg].y + v[sg].z + v[sg].w;
  }
#pragma unroll
  for (int off = 32; off > 0; off >>= 1) s += __shfl_xor(s, off);
  float mean = s * (1.f / DIMX);
  float sq = 0.f;
#pragma unroll
  for (int sg = 0; sg < 4; sg++) {
    float dx = v[sg].x - mean, dy = v[sg].y - mean, dz = v[sg].z - mean, dw = v[sg].w - mean;
    sq += dx * dx + dy * dy + dz * dz + dw * dw;
  }
#pragma unroll
  for (int off = 32; off > 0; off >>= 1) sq += __shfl_xor(sq, off);
  float rstd = rsqrtf(sq * (1.f / DIMX) + 1e-5f);
  float4* o4 = (float4*)(out + (size_t)t * DIMX);
#pragma unroll
  for (int sg = 0; sg < 4; sg++) {
    int idx = sg * 64 + lane;
    float4 g = ((const float4*)lg)[idx], bb = ((const float4*)lb)[idx];
    float4 o;
    o.x = (v[sg].x - mean) * rstd * g.x + bb.x;
    o.y = (v[sg].y - mean) * rstd * g.y + bb.y;
    o.z = (v[sg].z - mean) * rstd * g.z + bb.z;
    o.w = (v[sg].w - mean) * rstd * g.w + bb.w;
    o4[idx] = o;
  }
}

extern "C" void kernel_launch(void* const* d_in, const int* in_sizes, int n_in,
                              void* d_out, int out_size, void* d_ws, size_t ws_size,
                              hipStream_t stream) {
  const float* x     = (const float*)d_in[0];
  const float* gw    = (const float*)d_in[1];
  const float* w1    = (const float*)d_in[2];
  const float* b1    = (const float*)d_in[3];
  const float* ln1g  = (const float*)d_in[4];
  const float* ln1b  = (const float*)d_in[5];
  const float* w2    = (const float*)d_in[6];
  const float* b2    = (const float*)d_in[7];
  const float* lng   = (const float*)d_in[8];
  const float* lnb   = (const float*)d_in[9];
  float* out = (float*)d_out;

  char* ws = (char*)d_ws;
  int* cnt   = (int*)(ws + O_CNT);
  int* ptok  = (int*)(ws + O_TOK);
  int* ptk   = (int*)(ws + O_TK);
  float* pw  = (float*)(ws + O_PW);
  int* ti    = (int*)(ws + O_TI);
  float* tw  = (float*)(ws + O_TW);
  int* poffs = (int*)(ws + O_POFF);
  int* s_e   = (int*)(ws + O_SE);
  int* s_r0  = (int*)(ws + O_SR0);
  unsigned short* xbf  = (unsigned short*)(ws + O_XBF);
  unsigned short* w1t  = (unsigned short*)(ws + O_W1T);
  unsigned short* w2t  = (unsigned short*)(ws + O_W2T);
  unsigned short* hpre = (unsigned short*)(ws + O_H);
  float* ybuf = (float*)(ws + O_Y);

  hipLaunchKernelGGL(k_gate_cvt, dim3(NT / 4), dim3(256), 0, stream, x, gw, xbf, ti, tw);
  hipLaunchKernelGGL(k_build, dim3(1), dim3(512), 0, stream, ti, tw, cnt, poffs, s_e, s_r0,
                     ptok, ptk, pw);
  hipLaunchKernelGGL(k_transpose_cvt, dim3(HID / 64, DIMX / 64, NE), dim3(256), 0, stream,
                     w1, w1t, DIMX, HID);
  hipLaunchKernelGGL(k_transpose_cvt, dim3(DIMX / 64, HID / 64, NE), dim3(256), 0, stream,
                     w2, w2t, HID, DIMX);
  hipLaunchKernelGGL(k_gemm1, dim3(HID / BN, MAXSTRIP), dim3(256), 0, stream,
                     xbf, w1t, b1, cnt, s_e, s_r0, poffs, ptok, hpre);
  hipLaunchKernelGGL(k_ln_gelu, dim3(MAXSTRIP * BM / 4), dim3(256), 0, stream,
                     hpre, ln1g, ln1b, s_e);
  hipLaunchKernelGGL(k_gemm2, dim3(DIMX / BN, MAXSTRIP), dim3(256), 0, stream,
                     hpre, w2t, b2, cnt, s_e, s_r0, poffs, ptk, pw, ybuf);
  hipLaunchKernelGGL(k_final, dim3(NT / 4), dim3(256), 0, stream, ybuf, x, lng, lnb, out);
}